// Round 1
// baseline (2145.972 us; speedup 1.0000x reference)
//
#include <hip/hip_runtime.h>

#define SEQ 2048
#define DIM 512
#define HEADS 8
#define HD 64
#define WIN 128

struct ProjArgs {
  const float* W[6];
  const float* b[6];
  float* out[6];
};

// ---------------- Projection GEMM: out[p] = X @ W[p]^T + b[p] (head-major) ----
__global__ __launch_bounds__(256) void proj_kernel(const float* __restrict__ X, ProjArgs a) {
  const int p = blockIdx.z;
  const float* __restrict__ W = a.W[p];
  const float* __restrict__ bias = a.b[p];
  float* __restrict__ out = a.out[p];
  const float scale = (p == 0 || p == 3) ? 0.125f : 1.0f;  // q and qg pre-scaled

  __shared__ float As[32][64];  // As[kk][m]
  __shared__ float Bs[32][64];  // Bs[kk][n]

  const int m0 = blockIdx.x * 64;
  const int n0 = blockIdx.y * 64;
  const int t = threadIdx.x;
  const int tx = t & 15;
  const int ty = t >> 4;

  float acc[4][4];
#pragma unroll
  for (int i = 0; i < 4; ++i)
#pragma unroll
    for (int j = 0; j < 4; ++j) acc[i][j] = 0.0f;

  for (int k0 = 0; k0 < DIM; k0 += 32) {
#pragma unroll
    for (int l = 0; l < 2; ++l) {
      const int f = t + l * 256;
      const int m = f >> 3;   // 0..63
      const int kc = f & 7;   // 0..7 (float4 chunk)
      const float4 av = *(const float4*)&X[(size_t)(m0 + m) * DIM + k0 + kc * 4];
      As[kc * 4 + 0][m] = av.x;
      As[kc * 4 + 1][m] = av.y;
      As[kc * 4 + 2][m] = av.z;
      As[kc * 4 + 3][m] = av.w;
      const float4 bv = *(const float4*)&W[(size_t)(n0 + m) * DIM + k0 + kc * 4];
      Bs[kc * 4 + 0][m] = bv.x;
      Bs[kc * 4 + 1][m] = bv.y;
      Bs[kc * 4 + 2][m] = bv.z;
      Bs[kc * 4 + 3][m] = bv.w;
    }
    __syncthreads();
#pragma unroll
    for (int kk = 0; kk < 32; ++kk) {
      const float4 av = *(const float4*)&As[kk][ty * 4];
      const float4 bv = *(const float4*)&Bs[kk][tx * 4];
      const float am[4] = {av.x, av.y, av.z, av.w};
      const float bn[4] = {bv.x, bv.y, bv.z, bv.w};
#pragma unroll
      for (int i = 0; i < 4; ++i)
#pragma unroll
        for (int j = 0; j < 4; ++j) acc[i][j] = fmaf(am[i], bn[j], acc[i][j]);
    }
    __syncthreads();
  }

  const int head = n0 >> 6;  // == blockIdx.y (BN == HD)
#pragma unroll
  for (int i = 0; i < 4; ++i) {
    const int m = m0 + ty * 4 + i;
    float4 o;
    o.x = (acc[i][0] + bias[n0 + tx * 4 + 0]) * scale;
    o.y = (acc[i][1] + bias[n0 + tx * 4 + 1]) * scale;
    o.z = (acc[i][2] + bias[n0 + tx * 4 + 2]) * scale;
    o.w = (acc[i][3] + bias[n0 + tx * 4 + 3]) * scale;
    *(float4*)&out[((size_t)head * SEQ + m) * HD + tx * 4] = o;
  }
}

// ---------------- reduction helpers ----------------
__device__ inline float wave_max(float x) {
#pragma unroll
  for (int o = 32; o > 0; o >>= 1) x = fmaxf(x, __shfl_xor(x, o));
  return x;
}
__device__ inline float wave_sum(float x) {
#pragma unroll
  for (int o = 32; o > 0; o >>= 1) x += __shfl_xor(x, o);
  return x;
}

// ---------------- Local (banded + global-col) attention ----------------
__global__ __launch_bounds__(256) void local_attn_kernel(
    const float* __restrict__ q, const float* __restrict__ k,
    const float* __restrict__ v, const int* __restrict__ mask,
    float* __restrict__ out, float* __restrict__ attn) {
  const int i = blockIdx.x;
  const int h = blockIdx.y;
  const int t = threadIdx.x;
  const int mi = mask[i];

  if (mi == 0) {  // pad query: attn row stays 0 (memset), ctx = 0
    if (t < HD) out[(size_t)i * DIM + h * HD + t] = 0.0f;
    return;
  }

  __shared__ float qrow[HD];
  __shared__ float sc[SEQ];
  __shared__ float red[8];
  __shared__ float ctxp[4][HD];

  const bool allrow = (mi == -1);  // global query: all non-pad cols allowed
  if (t < HD) qrow[t] = q[((size_t)h * SEQ + i) * HD + t];
  __syncthreads();

  // ---- scores over allowed columns only ----
  float lmax = -1e30f;
  for (int c = t; c < SEQ; c += 256) {
    const int mc = mask[c];
    const int dist = (i > c) ? (i - c) : (c - i);
    const bool ok = (mc != 0) && (allrow || mc == -1 || dist <= WIN);
    float s = -1e30f;
    if (ok) {
      const float* kr = &k[((size_t)h * SEQ + c) * HD];
      float a0 = 0.f, a1 = 0.f, a2 = 0.f, a3 = 0.f;
#pragma unroll
      for (int d = 0; d < HD; d += 4) {
        const float4 kv = *(const float4*)&kr[d];
        const float4 qv = *(const float4*)&qrow[d];
        a0 = fmaf(qv.x, kv.x, a0);
        a1 = fmaf(qv.y, kv.y, a1);
        a2 = fmaf(qv.z, kv.z, a2);
        a3 = fmaf(qv.w, kv.w, a3);
      }
      s = (a0 + a1) + (a2 + a3);
      lmax = fmaxf(lmax, s);
    }
    sc[c] = s;
  }

  // ---- block max ----
  const float wm = wave_max(lmax);
  if ((t & 63) == 0) red[t >> 6] = wm;
  __syncthreads();
  const float rmax = fmaxf(fmaxf(red[0], red[1]), fmaxf(red[2], red[3]));

  // ---- exp + sum ----
  float lsum = 0.f;
  for (int c = t; c < SEQ; c += 256) {
    const float s = sc[c];
    const float pp = (s > -1e29f) ? __expf(s - rmax) : 0.0f;
    sc[c] = pp;
    lsum += pp;
  }
  const float wsum = wave_sum(lsum);
  __syncthreads();
  if ((t & 63) == 0) red[4 + (t >> 6)] = wsum;
  __syncthreads();
  const float rsum = (red[4] + red[5]) + (red[6] + red[7]);
  const float inv = 1.0f / rsum;

  // ---- write nonzero attn entries (rest are memset 0) ----
  float* __restrict__ arow = attn + (size_t)h * SEQ * SEQ + (size_t)i * SEQ;
  for (int c = t; c < SEQ; c += 256) {
    const float pp = sc[c];
    if (pp != 0.0f) arow[c] = pp * inv;
  }

  // ---- PV: wave-per-column (wave-uniform skip of zero columns) ----
  const int wv = t >> 6;
  const int d = t & 63;
  float ctx = 0.f;
  for (int c = wv; c < SEQ; c += 4) {
    const float pp = sc[c];
    if (pp != 0.0f) ctx = fmaf(pp, v[((size_t)h * SEQ + c) * HD + d], ctx);
  }
  ctxp[wv][d] = ctx;
  __syncthreads();
  if (t < HD) {
    const float r = ((ctxp[0][t] + ctxp[1][t]) + (ctxp[2][t] + ctxp[3][t])) * inv;
    out[(size_t)i * DIM + h * HD + t] = r;
  }
}

// ---------------- Global attention: only rows with mask == -1 ----------------
__global__ __launch_bounds__(256) void global_attn_kernel(
    const float* __restrict__ qg, const float* __restrict__ kg,
    const float* __restrict__ vg, const int* __restrict__ mask,
    float* __restrict__ out) {
  const int i = blockIdx.x;
  if (mask[i] != -1) return;  // uniform early exit
  const int h = blockIdx.y;
  const int t = threadIdx.x;

  __shared__ float qrow[HD];
  __shared__ float sc[SEQ];
  __shared__ float red[8];
  __shared__ float ctxp[4][HD];

  if (t < HD) qrow[t] = qg[((size_t)h * SEQ + i) * HD + t];
  __syncthreads();

  float lmax = -1e30f;
  for (int c = t; c < SEQ; c += 256) {
    float s = -1e30f;
    if (mask[c] != 0) {
      const float* kr = &kg[((size_t)h * SEQ + c) * HD];
      float a0 = 0.f, a1 = 0.f, a2 = 0.f, a3 = 0.f;
#pragma unroll
      for (int d = 0; d < HD; d += 4) {
        const float4 kv = *(const float4*)&kr[d];
        const float4 qv = *(const float4*)&qrow[d];
        a0 = fmaf(qv.x, kv.x, a0);
        a1 = fmaf(qv.y, kv.y, a1);
        a2 = fmaf(qv.z, kv.z, a2);
        a3 = fmaf(qv.w, kv.w, a3);
      }
      s = (a0 + a1) + (a2 + a3);
      lmax = fmaxf(lmax, s);
    }
    sc[c] = s;
  }

  const float wm = wave_max(lmax);
  if ((t & 63) == 0) red[t >> 6] = wm;
  __syncthreads();
  const float rmax = fmaxf(fmaxf(red[0], red[1]), fmaxf(red[2], red[3]));

  float lsum = 0.f;
  for (int c = t; c < SEQ; c += 256) {
    const float s = sc[c];
    const float pp = (s > -1e29f) ? __expf(s - rmax) : 0.0f;
    sc[c] = pp;
    lsum += pp;
  }
  const float wsum = wave_sum(lsum);
  __syncthreads();
  if ((t & 63) == 0) red[4 + (t >> 6)] = wsum;
  __syncthreads();
  const float rsum = (red[4] + red[5]) + (red[6] + red[7]);
  const float inv = 1.0f / rsum;

  const int wv = t >> 6;
  const int d = t & 63;
  float ctx = 0.f;
  for (int c = wv; c < SEQ; c += 4) {
    const float pp = sc[c];
    if (pp != 0.0f) ctx = fmaf(pp, vg[((size_t)h * SEQ + c) * HD + d], ctx);
  }
  ctxp[wv][d] = ctx;
  __syncthreads();
  if (t < HD) {
    const float r = ((ctxp[0][t] + ctxp[1][t]) + (ctxp[2][t] + ctxp[3][t])) * inv;
    out[(size_t)i * DIM + h * HD + t] = r;  // overwrite local ctx for global rows
  }
}

// ---------------- host ----------------
extern "C" void kernel_launch(void* const* d_in, const int* in_sizes, int n_in,
                              void* d_out, int out_size, void* d_ws, size_t ws_size,
                              hipStream_t stream) {
  const float* hs = (const float*)d_in[0];
  const int* mask = (const int*)d_in[13];

  float* q  = (float*)d_ws;                 // [H][S][64] each, 4 MB each
  float* kx = q  + (size_t)SEQ * DIM;
  float* vx = kx + (size_t)SEQ * DIM;
  float* qg = vx + (size_t)SEQ * DIM;
  float* kg = qg + (size_t)SEQ * DIM;
  float* vg = kg + (size_t)SEQ * DIM;

  float* out  = (float*)d_out;                    // [1,S,DIM]
  float* attn = out + (size_t)SEQ * DIM;          // [1,H,S,S]

  hipMemsetAsync(attn, 0, (size_t)HEADS * SEQ * SEQ * sizeof(float), stream);

  ProjArgs pa;
  pa.W[0] = (const float*)d_in[1];  pa.b[0] = (const float*)d_in[2];  pa.out[0] = q;
  pa.W[1] = (const float*)d_in[3];  pa.b[1] = (const float*)d_in[4];  pa.out[1] = kx;
  pa.W[2] = (const float*)d_in[5];  pa.b[2] = (const float*)d_in[6];  pa.out[2] = vx;
  pa.W[3] = (const float*)d_in[7];  pa.b[3] = (const float*)d_in[8];  pa.out[3] = qg;
  pa.W[4] = (const float*)d_in[9];  pa.b[4] = (const float*)d_in[10]; pa.out[4] = kg;
  pa.W[5] = (const float*)d_in[11]; pa.b[5] = (const float*)d_in[12]; pa.out[5] = vg;

  dim3 g1(SEQ / 64, DIM / 64, 6);
  hipLaunchKernelGGL(proj_kernel, g1, dim3(256), 0, stream, hs, pa);

  dim3 g2(SEQ, HEADS);
  hipLaunchKernelGGL(local_attn_kernel, g2, dim3(256), 0, stream, q, kx, vx, mask, out, attn);
  hipLaunchKernelGGL(global_attn_kernel, g2, dim3(256), 0, stream, qg, kg, vg, mask, out);
}

// Round 2
// 1380.150 us; speedup vs baseline: 1.5549x; 1.5549x over previous
//
#include <hip/hip_runtime.h>

#define SEQ 2048
#define DIM 512
#define HEADS 8
#define HD 64
#define WIN 128

struct ProjArgs {
  const float* W[6];
  const float* b[6];
  float* out[6];
};

// ---------------- Projection GEMM: out[p] = X @ W[p]^T + b[p] (head-major) ----
__global__ __launch_bounds__(256) void proj_kernel(const float* __restrict__ X, ProjArgs a) {
  const int p = blockIdx.z;
  const float* __restrict__ W = a.W[p];
  const float* __restrict__ bias = a.b[p];
  float* __restrict__ out = a.out[p];
  const float scale = (p == 0 || p == 3) ? 0.125f : 1.0f;  // q and qg pre-scaled

  __shared__ float As[32][64];  // As[kk][m]
  __shared__ float Bs[32][64];  // Bs[kk][n]

  const int m0 = blockIdx.x * 64;
  const int n0 = blockIdx.y * 64;
  const int t = threadIdx.x;
  const int tx = t & 15;
  const int ty = t >> 4;

  float acc[4][4];
#pragma unroll
  for (int i = 0; i < 4; ++i)
#pragma unroll
    for (int j = 0; j < 4; ++j) acc[i][j] = 0.0f;

  for (int k0 = 0; k0 < DIM; k0 += 32) {
#pragma unroll
    for (int l = 0; l < 2; ++l) {
      const int f = t + l * 256;
      const int m = f >> 3;   // 0..63
      const int kc = f & 7;   // 0..7 (float4 chunk)
      const float4 av = *(const float4*)&X[(size_t)(m0 + m) * DIM + k0 + kc * 4];
      As[kc * 4 + 0][m] = av.x;
      As[kc * 4 + 1][m] = av.y;
      As[kc * 4 + 2][m] = av.z;
      As[kc * 4 + 3][m] = av.w;
      const float4 bv = *(const float4*)&W[(size_t)(n0 + m) * DIM + k0 + kc * 4];
      Bs[kc * 4 + 0][m] = bv.x;
      Bs[kc * 4 + 1][m] = bv.y;
      Bs[kc * 4 + 2][m] = bv.z;
      Bs[kc * 4 + 3][m] = bv.w;
    }
    __syncthreads();
#pragma unroll
    for (int kk = 0; kk < 32; ++kk) {
      const float4 av = *(const float4*)&As[kk][ty * 4];
      const float4 bv = *(const float4*)&Bs[kk][tx * 4];
      const float am[4] = {av.x, av.y, av.z, av.w};
      const float bn[4] = {bv.x, bv.y, bv.z, bv.w};
#pragma unroll
      for (int i = 0; i < 4; ++i)
#pragma unroll
        for (int j = 0; j < 4; ++j) acc[i][j] = fmaf(am[i], bn[j], acc[i][j]);
    }
    __syncthreads();
  }

  const int head = n0 >> 6;  // == blockIdx.y (BN == HD)
#pragma unroll
  for (int i = 0; i < 4; ++i) {
    const int m = m0 + ty * 4 + i;
    float4 o;
    o.x = (acc[i][0] + bias[n0 + tx * 4 + 0]) * scale;
    o.y = (acc[i][1] + bias[n0 + tx * 4 + 1]) * scale;
    o.z = (acc[i][2] + bias[n0 + tx * 4 + 2]) * scale;
    o.w = (acc[i][3] + bias[n0 + tx * 4 + 3]) * scale;
    *(float4*)&out[((size_t)head * SEQ + m) * HD + tx * 4] = o;
  }
}

// ---------------- setup: ordered compact list of global columns ----------------
__global__ __launch_bounds__(256) void setup_kernel(const int* __restrict__ mask,
                                                    int* __restrict__ g) {
  __shared__ int cnt[256];
  const int t = threadIdx.x;
  int loc[8];
  int n = 0;
  const int base = t * 8;  // SEQ == 256*8, contiguous chunks -> ordered list
#pragma unroll
  for (int j = 0; j < 8; ++j) {
    const int c = base + j;
    if (mask[c] == -1) loc[n++] = c;
  }
  cnt[t] = n;
  __syncthreads();
  if (t == 0) {
    int acc = 0;
    for (int i = 0; i < 256; ++i) { const int v = cnt[i]; cnt[i] = acc; acc += v; }
    g[0] = acc;
  }
  __syncthreads();
  const int off = cnt[t];
  for (int j = 0; j < n; ++j) g[1 + off + j] = loc[j];
}

// ---------------- reduction helpers ----------------
__device__ inline float wave_max(float x) {
#pragma unroll
  for (int o = 32; o > 0; o >>= 1) x = fmaxf(x, __shfl_xor(x, o));
  return x;
}
__device__ inline float wave_sum(float x) {
#pragma unroll
  for (int o = 32; o > 0; o >>= 1) x += __shfl_xor(x, o);
  return x;
}

// ---------------- Local (banded + global-col) attention, compact slots --------
// slots for normal rows: [0, blen) -> band col lo+j ; [blen, blen+nglob) -> g[j-blen]
// slots for global rows: [0, SEQ)  -> col j
__global__ __launch_bounds__(256) void local_attn_kernel(
    const float* __restrict__ q, const float* __restrict__ k,
    const float* __restrict__ v, const int* __restrict__ mask,
    const int* __restrict__ g, float* __restrict__ out,
    float* __restrict__ attn) {
  const int i = blockIdx.x;
  const int h = blockIdx.y;
  const int t = threadIdx.x;
  const int mi = mask[i];

  if (mi == 0) {  // pad query: attn row stays 0 (memset), ctx = 0
    if (t < HD) out[(size_t)i * DIM + h * HD + t] = 0.0f;
    return;
  }

  __shared__ float sc[SEQ + 512];  // worst case blen(257) + nglob(2048) = 2305
  __shared__ float qrow[HD];
  __shared__ float red[8];
  __shared__ float ctxp[4][HD];

  const bool grow = (mi == -1);
  const int nglob = g[0];
  const int lo = grow ? 0 : ((i - WIN) > 0 ? (i - WIN) : 0);
  const int hi = grow ? (SEQ - 1) : ((i + WIN) < (SEQ - 1) ? (i + WIN) : (SEQ - 1));
  const int blen = hi - lo + 1;
  const int nslots = grow ? SEQ : (blen + nglob);

  if (t < HD) qrow[t] = q[((size_t)h * SEQ + i) * HD + t];
  __syncthreads();

  // ---- scores on allowed slots ----
  float lmax = -1e30f;
  for (int j = t; j < nslots; j += 256) {
    int c;
    bool ok;
    if (grow) { c = j; ok = (mask[c] != 0); }
    else if (j < blen) { c = lo + j; ok = (mask[c] != 0); }
    else { c = g[1 + j - blen]; ok = (c < lo || c > hi); }  // dedupe in-band globs
    float s = -1e30f;
    if (ok) {
      const float* kr = &k[((size_t)h * SEQ + c) * HD];
      float a0 = 0.f, a1 = 0.f, a2 = 0.f, a3 = 0.f;
#pragma unroll
      for (int d = 0; d < HD; d += 4) {
        const float4 kv = *(const float4*)&kr[d];
        const float4 qv = *(const float4*)&qrow[d];
        a0 = fmaf(qv.x, kv.x, a0);
        a1 = fmaf(qv.y, kv.y, a1);
        a2 = fmaf(qv.z, kv.z, a2);
        a3 = fmaf(qv.w, kv.w, a3);
      }
      s = (a0 + a1) + (a2 + a3);
      lmax = fmaxf(lmax, s);
    }
    sc[j] = s;
  }

  // ---- block max ----
  const float wm = wave_max(lmax);
  if ((t & 63) == 0) red[t >> 6] = wm;
  __syncthreads();
  const float rmax = fmaxf(fmaxf(red[0], red[1]), fmaxf(red[2], red[3]));

  // ---- exp + sum ----
  float lsum = 0.f;
  for (int j = t; j < nslots; j += 256) {
    const float s = sc[j];
    const float pp = (s > -1e29f) ? __expf(s - rmax) : 0.0f;
    sc[j] = pp;
    lsum += pp;
  }
  const float wsum = wave_sum(lsum);
  __syncthreads();
  if ((t & 63) == 0) red[4 + (t >> 6)] = wsum;
  __syncthreads();
  const float rsum = (red[4] + red[5]) + (red[6] + red[7]);
  const float inv = 1.0f / rsum;

  // ---- write nonzero attn entries (rest are memset 0) ----
  float* __restrict__ arow = attn + (size_t)h * SEQ * SEQ + (size_t)i * SEQ;
  for (int j = t; j < nslots; j += 256) {
    const float pp = sc[j];
    if (pp != 0.0f) {
      const int c = grow ? j : (j < blen ? lo + j : g[1 + j - blen]);
      arow[c] = pp * inv;
    }
  }

  if (grow) return;  // ctx for global rows is overwritten by global_attn

  // ---- PV: wave-per-slot ----
  const int wv = t >> 6;
  const int d = t & 63;
  float ctx = 0.f;
  for (int j = wv; j < nslots; j += 4) {
    const float pp = sc[j];
    if (pp != 0.0f) {
      const int c = (j < blen) ? lo + j : g[1 + j - blen];
      ctx = fmaf(pp, v[((size_t)h * SEQ + c) * HD + d], ctx);
    }
  }
  ctxp[wv][d] = ctx;
  __syncthreads();
  if (t < HD) {
    const float r = ((ctxp[0][t] + ctxp[1][t]) + (ctxp[2][t] + ctxp[3][t])) * inv;
    out[(size_t)i * DIM + h * HD + t] = r;
  }
}

// ---------------- Global attention: only rows with mask == -1 ----------------
__global__ __launch_bounds__(256) void global_attn_kernel(
    const float* __restrict__ qg, const float* __restrict__ kg,
    const float* __restrict__ vg, const int* __restrict__ mask,
    float* __restrict__ out) {
  const int i = blockIdx.x;
  if (mask[i] != -1) return;  // uniform early exit
  const int h = blockIdx.y;
  const int t = threadIdx.x;

  __shared__ float qrow[HD];
  __shared__ float sc[SEQ];
  __shared__ float red[8];
  __shared__ float ctxp[4][HD];

  if (t < HD) qrow[t] = qg[((size_t)h * SEQ + i) * HD + t];
  __syncthreads();

  float lmax = -1e30f;
  for (int c = t; c < SEQ; c += 256) {
    float s = -1e30f;
    if (mask[c] != 0) {
      const float* kr = &kg[((size_t)h * SEQ + c) * HD];
      float a0 = 0.f, a1 = 0.f, a2 = 0.f, a3 = 0.f;
#pragma unroll
      for (int d = 0; d < HD; d += 4) {
        const float4 kv = *(const float4*)&kr[d];
        const float4 qv = *(const float4*)&qrow[d];
        a0 = fmaf(qv.x, kv.x, a0);
        a1 = fmaf(qv.y, kv.y, a1);
        a2 = fmaf(qv.z, kv.z, a2);
        a3 = fmaf(qv.w, kv.w, a3);
      }
      s = (a0 + a1) + (a2 + a3);
      lmax = fmaxf(lmax, s);
    }
    sc[c] = s;
  }

  const float wm = wave_max(lmax);
  if ((t & 63) == 0) red[t >> 6] = wm;
  __syncthreads();
  const float rmax = fmaxf(fmaxf(red[0], red[1]), fmaxf(red[2], red[3]));

  float lsum = 0.f;
  for (int c = t; c < SEQ; c += 256) {
    const float s = sc[c];
    const float pp = (s > -1e29f) ? __expf(s - rmax) : 0.0f;
    sc[c] = pp;
    lsum += pp;
  }
  const float wsum = wave_sum(lsum);
  __syncthreads();
  if ((t & 63) == 0) red[4 + (t >> 6)] = wsum;
  __syncthreads();
  const float rsum = (red[4] + red[5]) + (red[6] + red[7]);
  const float inv = 1.0f / rsum;

  const int wv = t >> 6;
  const int d = t & 63;
  float ctx = 0.f;
  for (int c = wv; c < SEQ; c += 4) {
    const float pp = sc[c];
    if (pp != 0.0f) ctx = fmaf(pp, vg[((size_t)h * SEQ + c) * HD + d], ctx);
  }
  ctxp[wv][d] = ctx;
  __syncthreads();
  if (t < HD) {
    const float r = ((ctxp[0][t] + ctxp[1][t]) + (ctxp[2][t] + ctxp[3][t])) * inv;
    out[(size_t)i * DIM + h * HD + t] = r;  // overwrite local ctx for global rows
  }
}

// ---------------- host ----------------
extern "C" void kernel_launch(void* const* d_in, const int* in_sizes, int n_in,
                              void* d_out, int out_size, void* d_ws, size_t ws_size,
                              hipStream_t stream) {
  const float* hs = (const float*)d_in[0];
  const int* mask = (const int*)d_in[13];

  float* q  = (float*)d_ws;                 // [H][S][64] each, 4 MB each
  float* kx = q  + (size_t)SEQ * DIM;
  float* vx = kx + (size_t)SEQ * DIM;
  float* qg = vx + (size_t)SEQ * DIM;
  float* kg = qg + (size_t)SEQ * DIM;
  float* vg = kg + (size_t)SEQ * DIM;
  int* gcols = (int*)(vg + (size_t)SEQ * DIM);  // [1 + SEQ]

  float* out  = (float*)d_out;                    // [1,S,DIM]
  float* attn = out + (size_t)SEQ * DIM;          // [1,H,S,S]

  hipMemsetAsync(attn, 0, (size_t)HEADS * SEQ * SEQ * sizeof(float), stream);

  hipLaunchKernelGGL(setup_kernel, dim3(1), dim3(256), 0, stream, mask, gcols);

  ProjArgs pa;
  pa.W[0] = (const float*)d_in[1];  pa.b[0] = (const float*)d_in[2];  pa.out[0] = q;
  pa.W[1] = (const float*)d_in[3];  pa.b[1] = (const float*)d_in[4];  pa.out[1] = kx;
  pa.W[2] = (const float*)d_in[5];  pa.b[2] = (const float*)d_in[6];  pa.out[2] = vx;
  pa.W[3] = (const float*)d_in[7];  pa.b[3] = (const float*)d_in[8];  pa.out[3] = qg;
  pa.W[4] = (const float*)d_in[9];  pa.b[4] = (const float*)d_in[10]; pa.out[4] = kg;
  pa.W[5] = (const float*)d_in[11]; pa.b[5] = (const float*)d_in[12]; pa.out[5] = vg;

  dim3 g1(SEQ / 64, DIM / 64, 6);
  hipLaunchKernelGGL(proj_kernel, g1, dim3(256), 0, stream, hs, pa);

  dim3 g2(SEQ, HEADS);
  hipLaunchKernelGGL(local_attn_kernel, g2, dim3(256), 0, stream, q, kx, vx, mask, gcols, out, attn);
  hipLaunchKernelGGL(global_attn_kernel, g2, dim3(256), 0, stream, qg, kg, vg, mask, out);
}

// Round 3
// 495.532 us; speedup vs baseline: 4.3306x; 2.7852x over previous
//
#include <hip/hip_runtime.h>

#define SEQ 2048
#define DIM 512
#define HEADS 8
#define HD 64
#define WIN 128

struct ProjArgs {
  const float* W[6];
  const float* b[6];
  float* out[6];
};

// ---------------- Projection GEMM: out[p] = X @ W[p]^T + b[p] (head-major) ----
__global__ __launch_bounds__(256) void proj_kernel(const float* __restrict__ X, ProjArgs a) {
  const int p = blockIdx.z;
  const float* __restrict__ W = a.W[p];
  const float* __restrict__ bias = a.b[p];
  float* __restrict__ out = a.out[p];
  const float scale = (p == 0 || p == 3) ? 0.125f : 1.0f;  // q and qg pre-scaled

  __shared__ float As[32][64];  // As[kk][m]
  __shared__ float Bs[32][64];  // Bs[kk][n]

  const int m0 = blockIdx.x * 64;
  const int n0 = blockIdx.y * 64;
  const int t = threadIdx.x;
  const int tx = t & 15;
  const int ty = t >> 4;

  float acc[4][4];
#pragma unroll
  for (int i = 0; i < 4; ++i)
#pragma unroll
    for (int j = 0; j < 4; ++j) acc[i][j] = 0.0f;

  for (int k0 = 0; k0 < DIM; k0 += 32) {
#pragma unroll
    for (int l = 0; l < 2; ++l) {
      const int f = t + l * 256;
      const int m = f >> 3;   // 0..63
      const int kc = f & 7;   // 0..7 (float4 chunk)
      const float4 av = *(const float4*)&X[(size_t)(m0 + m) * DIM + k0 + kc * 4];
      As[kc * 4 + 0][m] = av.x;
      As[kc * 4 + 1][m] = av.y;
      As[kc * 4 + 2][m] = av.z;
      As[kc * 4 + 3][m] = av.w;
      const float4 bv = *(const float4*)&W[(size_t)(n0 + m) * DIM + k0 + kc * 4];
      Bs[kc * 4 + 0][m] = bv.x;
      Bs[kc * 4 + 1][m] = bv.y;
      Bs[kc * 4 + 2][m] = bv.z;
      Bs[kc * 4 + 3][m] = bv.w;
    }
    __syncthreads();
#pragma unroll
    for (int kk = 0; kk < 32; ++kk) {
      const float4 av = *(const float4*)&As[kk][ty * 4];
      const float4 bv = *(const float4*)&Bs[kk][tx * 4];
      const float am[4] = {av.x, av.y, av.z, av.w};
      const float bn[4] = {bv.x, bv.y, bv.z, bv.w};
#pragma unroll
      for (int i = 0; i < 4; ++i)
#pragma unroll
        for (int j = 0; j < 4; ++j) acc[i][j] = fmaf(am[i], bn[j], acc[i][j]);
    }
    __syncthreads();
  }

  const int head = n0 >> 6;  // == blockIdx.y (BN == HD)
#pragma unroll
  for (int i = 0; i < 4; ++i) {
    const int m = m0 + ty * 4 + i;
    float4 o;
    o.x = (acc[i][0] + bias[n0 + tx * 4 + 0]) * scale;
    o.y = (acc[i][1] + bias[n0 + tx * 4 + 1]) * scale;
    o.z = (acc[i][2] + bias[n0 + tx * 4 + 2]) * scale;
    o.w = (acc[i][3] + bias[n0 + tx * 4 + 3]) * scale;
    *(float4*)&out[((size_t)head * SEQ + m) * HD + tx * 4] = o;
  }
}

// ---------------- setup: ordered compact list of global columns ----------------
__global__ __launch_bounds__(256) void setup_kernel(const int* __restrict__ mask,
                                                    int* __restrict__ g) {
  __shared__ int wtot[4];
  const int t = threadIdx.x;
  const int lane = t & 63;
  const int wv = t >> 6;
  int loc[8];
  int n = 0;
  const int base = t * 8;  // SEQ == 256*8, contiguous chunks -> ordered list
#pragma unroll
  for (int j = 0; j < 8; ++j) {
    const int c = base + j;
    if (mask[c] == -1) loc[n++] = c;
  }
  // wave-inclusive scan of n
  int x = n;
#pragma unroll
  for (int o = 1; o < 64; o <<= 1) {
    const int y = __shfl_up(x, o);
    if (lane >= o) x += y;
  }
  if (lane == 63) wtot[wv] = x;
  __syncthreads();
  int basew = 0;
  for (int w = 0; w < wv; ++w) basew += wtot[w];
  if (t == 255) g[0] = basew + x;
  const int off = basew + x - n;
  for (int j = 0; j < n; ++j) g[1 + off + j] = loc[j];
}

// ---------------- reduction helpers ----------------
__device__ inline float wave_max(float x) {
#pragma unroll
  for (int o = 32; o > 0; o >>= 1) x = fmaxf(x, __shfl_xor(x, o));
  return x;
}
__device__ inline float wave_sum(float x) {
#pragma unroll
  for (int o = 32; o > 0; o >>= 1) x += __shfl_xor(x, o);
  return x;
}

// ---------------- Local banded attention (non-global, non-pad rows) ----------
// slots: [0, blen) -> band col lo+j ; [blen, blen+nglob) -> g[j-blen]
__global__ __launch_bounds__(256) void local_attn_kernel(
    const float* __restrict__ q, const float* __restrict__ k,
    const float* __restrict__ v, const int* __restrict__ mask,
    const int* __restrict__ g, float* __restrict__ out,
    float* __restrict__ attn) {
  const int i = blockIdx.x;
  const int h = blockIdx.y;
  const int t = threadIdx.x;
  const int mi = mask[i];

  if (mi == 0) {  // pad query: attn row stays 0 (memset), ctx = 0
    if (t < HD) out[(size_t)i * DIM + h * HD + t] = 0.0f;
    return;
  }
  if (mi == -1) return;  // global rows handled by growrow/global kernels

  __shared__ float sc[WIN * 2 + 1 + 512];
  __shared__ float qrow[HD];
  __shared__ float red[8];
  __shared__ float ctxp[4][HD];

  const int nglob = g[0];
  const int lo = (i - WIN) > 0 ? (i - WIN) : 0;
  const int hi = (i + WIN) < (SEQ - 1) ? (i + WIN) : (SEQ - 1);
  const int blen = hi - lo + 1;
  const int nslots = blen + nglob;

  if (t < HD) qrow[t] = q[((size_t)h * SEQ + i) * HD + t];
  __syncthreads();

  // ---- scores on slots (unconditional dot, masked via select) ----
  float lmax = -1e30f;
  for (int j = t; j < nslots; j += 256) {
    int c;
    bool ok;
    if (j < blen) { c = lo + j; ok = (mask[c] != 0); }
    else { c = g[1 + j - blen]; ok = (c < lo || c > hi); }  // dedupe in-band globs
    const float* kr = &k[((size_t)h * SEQ + c) * HD];
    float a0 = 0.f, a1 = 0.f, a2 = 0.f, a3 = 0.f;
#pragma unroll
    for (int d = 0; d < HD; d += 4) {
      const float4 kv = *(const float4*)&kr[d];
      const float4 qv = *(const float4*)&qrow[d];
      a0 = fmaf(qv.x, kv.x, a0);
      a1 = fmaf(qv.y, kv.y, a1);
      a2 = fmaf(qv.z, kv.z, a2);
      a3 = fmaf(qv.w, kv.w, a3);
    }
    const float s = ok ? ((a0 + a1) + (a2 + a3)) : -1e30f;
    lmax = fmaxf(lmax, s);
    sc[j] = s;
  }

  const float wm = wave_max(lmax);
  if ((t & 63) == 0) red[t >> 6] = wm;
  __syncthreads();
  const float rmax = fmaxf(fmaxf(red[0], red[1]), fmaxf(red[2], red[3]));

  float lsum = 0.f;
  for (int j = t; j < nslots; j += 256) {
    const float s = sc[j];
    const float pp = (s > -1e29f) ? __expf(s - rmax) : 0.0f;
    sc[j] = pp;
    lsum += pp;
  }
  const float wsum = wave_sum(lsum);
  __syncthreads();
  if ((t & 63) == 0) red[4 + (t >> 6)] = wsum;
  __syncthreads();
  const float rsum = (red[4] + red[5]) + (red[6] + red[7]);
  const float inv = 1.0f / rsum;

  // ---- write nonzero attn entries (rest are memset 0) ----
  float* __restrict__ arow = attn + (size_t)h * SEQ * SEQ + (size_t)i * SEQ;
  for (int j = t; j < nslots; j += 256) {
    const float pp = sc[j];
    if (pp != 0.0f) {
      const int c = (j < blen) ? lo + j : g[1 + j - blen];
      arow[c] = pp * inv;
    }
  }

  // ---- PV: wave-per-slot, unconditional (pp==0 contributes 0) ----
  const int wv = t >> 6;
  const int d = t & 63;
  float ctx = 0.f;
#pragma unroll 4
  for (int j = wv; j < nslots; j += 4) {
    const float pp = sc[j];
    const int c = (j < blen) ? lo + j : g[1 + j - blen];
    ctx = fmaf(pp, v[((size_t)h * SEQ + c) * HD + d], ctx);
  }
  ctxp[wv][d] = ctx;
  __syncthreads();
  if (t < HD) {
    const float r = ((ctxp[0][t] + ctxp[1][t]) + (ctxp[2][t] + ctxp[3][t])) * inv;
    out[(size_t)i * DIM + h * HD + t] = r;
  }
}

// ------- local-attn probabilities for GLOBAL rows (compact grid, no ctx) -------
__global__ __launch_bounds__(256) void growrow_attn_kernel(
    const float* __restrict__ q, const float* __restrict__ k,
    const int* __restrict__ mask, const int* __restrict__ g,
    float* __restrict__ attn) {
  const int nglob = g[0];
  const int j0 = blockIdx.x >> 3;
  const int h = blockIdx.x & 7;
  const int t = threadIdx.x;

  __shared__ float sc[SEQ];
  __shared__ float qrow[HD];
  __shared__ float red[8];

  for (int jj = j0; jj < nglob; jj += 32) {
    const int i = g[1 + jj];
    __syncthreads();
    if (t < HD) qrow[t] = q[((size_t)h * SEQ + i) * HD + t];
    __syncthreads();

    float lmax = -1e30f;
#pragma unroll 2
    for (int c = t; c < SEQ; c += 256) {
      const bool ok = (mask[c] != 0);
      const float* kr = &k[((size_t)h * SEQ + c) * HD];
      float a0 = 0.f, a1 = 0.f, a2 = 0.f, a3 = 0.f;
#pragma unroll
      for (int d = 0; d < HD; d += 4) {
        const float4 kv = *(const float4*)&kr[d];
        const float4 qv = *(const float4*)&qrow[d];
        a0 = fmaf(qv.x, kv.x, a0);
        a1 = fmaf(qv.y, kv.y, a1);
        a2 = fmaf(qv.z, kv.z, a2);
        a3 = fmaf(qv.w, kv.w, a3);
      }
      const float s = ok ? ((a0 + a1) + (a2 + a3)) : -1e30f;
      lmax = fmaxf(lmax, s);
      sc[c] = s;
    }
    const float wm = wave_max(lmax);
    if ((t & 63) == 0) red[t >> 6] = wm;
    __syncthreads();
    const float rmax = fmaxf(fmaxf(red[0], red[1]), fmaxf(red[2], red[3]));

    float lsum = 0.f;
#pragma unroll 2
    for (int c = t; c < SEQ; c += 256) {
      const float s = sc[c];
      const float pp = (s > -1e29f) ? __expf(s - rmax) : 0.0f;
      sc[c] = pp;
      lsum += pp;
    }
    const float wsum = wave_sum(lsum);
    __syncthreads();
    if ((t & 63) == 0) red[4 + (t >> 6)] = wsum;
    __syncthreads();
    const float rsum = (red[4] + red[5]) + (red[6] + red[7]);
    const float inv = 1.0f / rsum;

    float* __restrict__ arow = attn + (size_t)h * SEQ * SEQ + (size_t)i * SEQ;
#pragma unroll 2
    for (int c = t; c < SEQ; c += 256) {
      const float pp = sc[c];
      if (pp != 0.0f) arow[c] = pp * inv;
    }
  }
}

// ---------------- Global attention branch (compact grid) ----------------
__global__ __launch_bounds__(256) void global_attn_kernel(
    const float* __restrict__ qg, const float* __restrict__ kg,
    const float* __restrict__ vg, const int* __restrict__ mask,
    const int* __restrict__ g, float* __restrict__ out) {
  const int nglob = g[0];
  const int j0 = blockIdx.x >> 3;
  const int h = blockIdx.x & 7;
  const int t = threadIdx.x;

  __shared__ float sc[SEQ];
  __shared__ float qrow[HD];
  __shared__ float red[8];
  __shared__ float ctxp[4][HD];

  for (int jj = j0; jj < nglob; jj += 32) {
    const int i = g[1 + jj];
    __syncthreads();
    if (t < HD) qrow[t] = qg[((size_t)h * SEQ + i) * HD + t];
    __syncthreads();

    float lmax = -1e30f;
#pragma unroll 2
    for (int c = t; c < SEQ; c += 256) {
      const bool ok = (mask[c] != 0);
      const float* kr = &kg[((size_t)h * SEQ + c) * HD];
      float a0 = 0.f, a1 = 0.f, a2 = 0.f, a3 = 0.f;
#pragma unroll
      for (int d = 0; d < HD; d += 4) {
        const float4 kv = *(const float4*)&kr[d];
        const float4 qv = *(const float4*)&qrow[d];
        a0 = fmaf(qv.x, kv.x, a0);
        a1 = fmaf(qv.y, kv.y, a1);
        a2 = fmaf(qv.z, kv.z, a2);
        a3 = fmaf(qv.w, kv.w, a3);
      }
      const float s = ok ? ((a0 + a1) + (a2 + a3)) : -1e30f;
      lmax = fmaxf(lmax, s);
      sc[c] = s;
    }
    const float wm = wave_max(lmax);
    if ((t & 63) == 0) red[t >> 6] = wm;
    __syncthreads();
    const float rmax = fmaxf(fmaxf(red[0], red[1]), fmaxf(red[2], red[3]));

    float lsum = 0.f;
#pragma unroll 2
    for (int c = t; c < SEQ; c += 256) {
      const float s = sc[c];
      const float pp = (s > -1e29f) ? __expf(s - rmax) : 0.0f;
      sc[c] = pp;
      lsum += pp;
    }
    const float wsum = wave_sum(lsum);
    __syncthreads();
    if ((t & 63) == 0) red[4 + (t >> 6)] = wsum;
    __syncthreads();
    const float rsum = (red[4] + red[5]) + (red[6] + red[7]);
    const float inv = 1.0f / rsum;

    // PV: wave-per-col, unconditional (pp==0 for pad cols)
    const int wv = t >> 6;
    const int d = t & 63;
    float ctx = 0.f;
#pragma unroll 8
    for (int c = wv; c < SEQ; c += 4) {
      ctx = fmaf(sc[c], vg[((size_t)h * SEQ + c) * HD + d], ctx);
    }
    ctxp[wv][d] = ctx;
    __syncthreads();
    if (t < HD) {
      const float r = ((ctxp[0][t] + ctxp[1][t]) + (ctxp[2][t] + ctxp[3][t])) * inv;
      out[(size_t)i * DIM + h * HD + t] = r;  // overwrite local ctx for global rows
    }
  }
}

// ---------------- host ----------------
extern "C" void kernel_launch(void* const* d_in, const int* in_sizes, int n_in,
                              void* d_out, int out_size, void* d_ws, size_t ws_size,
                              hipStream_t stream) {
  const float* hs = (const float*)d_in[0];
  const int* mask = (const int*)d_in[13];

  float* q  = (float*)d_ws;                 // [H][S][64] each, 4 MB each
  float* kx = q  + (size_t)SEQ * DIM;
  float* vx = kx + (size_t)SEQ * DIM;
  float* qg = vx + (size_t)SEQ * DIM;
  float* kg = qg + (size_t)SEQ * DIM;
  float* vg = kg + (size_t)SEQ * DIM;
  int* gcols = (int*)(vg + (size_t)SEQ * DIM);  // [1 + SEQ]

  float* out  = (float*)d_out;                    // [1,S,DIM]
  float* attn = out + (size_t)SEQ * DIM;          // [1,H,S,S]

  hipMemsetAsync(attn, 0, (size_t)HEADS * SEQ * SEQ * sizeof(float), stream);

  hipLaunchKernelGGL(setup_kernel, dim3(1), dim3(256), 0, stream, mask, gcols);

  ProjArgs pa;
  pa.W[0] = (const float*)d_in[1];  pa.b[0] = (const float*)d_in[2];  pa.out[0] = q;
  pa.W[1] = (const float*)d_in[3];  pa.b[1] = (const float*)d_in[4];  pa.out[1] = kx;
  pa.W[2] = (const float*)d_in[5];  pa.b[2] = (const float*)d_in[6];  pa.out[2] = vx;
  pa.W[3] = (const float*)d_in[7];  pa.b[3] = (const float*)d_in[8];  pa.out[3] = qg;
  pa.W[4] = (const float*)d_in[9];  pa.b[4] = (const float*)d_in[10]; pa.out[4] = kg;
  pa.W[5] = (const float*)d_in[11]; pa.b[5] = (const float*)d_in[12]; pa.out[5] = vg;

  dim3 g1(SEQ / 64, DIM / 64, 6);
  hipLaunchKernelGGL(proj_kernel, g1, dim3(256), 0, stream, hs, pa);

  dim3 g2(SEQ, HEADS);
  hipLaunchKernelGGL(local_attn_kernel, g2, dim3(256), 0, stream, q, kx, vx, mask, gcols, out, attn);
  hipLaunchKernelGGL(growrow_attn_kernel, dim3(256), dim3(256), 0, stream, q, kx, mask, gcols, attn);
  hipLaunchKernelGGL(global_attn_kernel, dim3(256), dim3(256), 0, stream, qg, kg, vg, mask, gcols, out);
}

// Round 4
// 266.298 us; speedup vs baseline: 8.0585x; 1.8608x over previous
//
#include <hip/hip_runtime.h>

#define SEQ 2048
#define DIM 512
#define HEADS 8
#define HD 64
#define WIN 128
#define NSMAX 320  // 288 band-union + up to 32 global cols

struct ProjArgs {
  const float* W[6];
  const float* b[6];
  float* out[6];
};

// ---------------- Projection GEMM: out[p] = X @ W[p]^T + b[p] (head-major) ----
__global__ __launch_bounds__(256) void proj_kernel(const float* __restrict__ X, ProjArgs a) {
  const int p = blockIdx.z;
  const float* __restrict__ W = a.W[p];
  const float* __restrict__ bias = a.b[p];
  float* __restrict__ out = a.out[p];
  const float scale = (p == 0 || p == 3) ? 0.125f : 1.0f;  // q and qg pre-scaled

  __shared__ float As[32][64];  // As[kk][m]
  __shared__ float Bs[32][64];  // Bs[kk][n]

  const int m0 = blockIdx.x * 64;
  const int n0 = blockIdx.y * 64;
  const int t = threadIdx.x;
  const int tx = t & 15;
  const int ty = t >> 4;

  float acc[4][4];
#pragma unroll
  for (int i = 0; i < 4; ++i)
#pragma unroll
    for (int j = 0; j < 4; ++j) acc[i][j] = 0.0f;

  for (int k0 = 0; k0 < DIM; k0 += 32) {
#pragma unroll
    for (int l = 0; l < 2; ++l) {
      const int f = t + l * 256;
      const int m = f >> 3;   // 0..63
      const int kc = f & 7;   // 0..7 (float4 chunk)
      const float4 av = *(const float4*)&X[(size_t)(m0 + m) * DIM + k0 + kc * 4];
      As[kc * 4 + 0][m] = av.x;
      As[kc * 4 + 1][m] = av.y;
      As[kc * 4 + 2][m] = av.z;
      As[kc * 4 + 3][m] = av.w;
      const float4 bv = *(const float4*)&W[(size_t)(n0 + m) * DIM + k0 + kc * 4];
      Bs[kc * 4 + 0][m] = bv.x;
      Bs[kc * 4 + 1][m] = bv.y;
      Bs[kc * 4 + 2][m] = bv.z;
      Bs[kc * 4 + 3][m] = bv.w;
    }
    __syncthreads();
#pragma unroll
    for (int kk = 0; kk < 32; ++kk) {
      const float4 av = *(const float4*)&As[kk][ty * 4];
      const float4 bv = *(const float4*)&Bs[kk][tx * 4];
      const float am[4] = {av.x, av.y, av.z, av.w};
      const float bn[4] = {bv.x, bv.y, bv.z, bv.w};
#pragma unroll
      for (int i = 0; i < 4; ++i)
#pragma unroll
        for (int j = 0; j < 4; ++j) acc[i][j] = fmaf(am[i], bn[j], acc[i][j]);
    }
    __syncthreads();
  }

  const int head = n0 >> 6;
#pragma unroll
  for (int i = 0; i < 4; ++i) {
    const int m = m0 + ty * 4 + i;
    float4 o;
    o.x = (acc[i][0] + bias[n0 + tx * 4 + 0]) * scale;
    o.y = (acc[i][1] + bias[n0 + tx * 4 + 1]) * scale;
    o.z = (acc[i][2] + bias[n0 + tx * 4 + 2]) * scale;
    o.w = (acc[i][3] + bias[n0 + tx * 4 + 3]) * scale;
    *(float4*)&out[((size_t)head * SEQ + m) * HD + tx * 4] = o;
  }
}

// ---------------- setup: ordered compact list of global columns ----------------
__global__ __launch_bounds__(256) void setup_kernel(const int* __restrict__ mask,
                                                    int* __restrict__ g) {
  __shared__ int wtot[4];
  const int t = threadIdx.x;
  const int lane = t & 63;
  const int wv = t >> 6;
  int loc[8];
  int n = 0;
  const int base = t * 8;
#pragma unroll
  for (int j = 0; j < 8; ++j) {
    const int c = base + j;
    if (mask[c] == -1) loc[n++] = c;
  }
  int x = n;
#pragma unroll
  for (int o = 1; o < 64; o <<= 1) {
    const int y = __shfl_up(x, o);
    if (lane >= o) x += y;
  }
  if (lane == 63) wtot[wv] = x;
  __syncthreads();
  int basew = 0;
  for (int w = 0; w < wv; ++w) basew += wtot[w];
  if (t == 255) g[0] = basew + x;
  const int off = basew + x - n;
  for (int j = 0; j < n; ++j) g[1 + off + j] = loc[j];
}

// ---------------- reduction helpers ----------------
__device__ inline float wave_max(float x) {
#pragma unroll
  for (int o = 32; o > 0; o >>= 1) x = fmaxf(x, __shfl_xor(x, o));
  return x;
}
__device__ inline float wave_sum(float x) {
#pragma unroll
  for (int o = 32; o > 0; o >>= 1) x += __shfl_xor(x, o);
  return x;
}

// ---------------- Tiled local attention: 32 query rows per block ----------------
// slots: [0, blen) -> band-union col lo+j ; [blen, nslots) -> global col (deduped)
__global__ __launch_bounds__(256) void local_attn_tile_kernel(
    const float* __restrict__ q, const float* __restrict__ k,
    const float* __restrict__ v, const int* __restrict__ mask,
    const int* __restrict__ g, float* __restrict__ out,
    float* __restrict__ attn) {
  const int h = blockIdx.y;
  const int r0 = blockIdx.x * 32;
  const int t = threadIdx.x;

  __shared__ float qs[32][68];      // Q tile  (stride 68: float4-aligned)
  __shared__ float ks[64][68];      // K/V chunk staging
  __shared__ float sct[NSMAX][36];  // scores->probs, slot-major
  __shared__ int scol[NSMAX];
  __shared__ int scm[NSMAX];
  __shared__ int mrow[32];
  __shared__ float pmax[8][32], psum[8][32];
  __shared__ float rmax[32], rinv[32];

  const int nglob_raw = g[0];
  const int nglob = nglob_raw < 32 ? nglob_raw : 32;
  const int lo = (r0 - WIN) > 0 ? (r0 - WIN) : 0;
  const int hi = (r0 + 31 + WIN) < (SEQ - 1) ? (r0 + 31 + WIN) : (SEQ - 1);
  const int blen = hi - lo + 1;
  const int nslots = blen + nglob;

  if (t < 32) mrow[t] = mask[r0 + t];
  for (int j = t; j < NSMAX; j += 256) {
    int c = 0;
    if (j < blen) c = lo + j;
    else if (j < nslots) c = g[1 + j - blen];
    scol[j] = c;
    scm[j] = mask[c];
  }
  // Q tile load: 512 float4
#pragma unroll
  for (int l = 0; l < 2; ++l) {
    const int idx = t + l * 256;
    const int r = idx >> 4, d4 = idx & 15;
    *(float4*)&qs[r][d4 * 4] =
        *(const float4*)&q[((size_t)h * SEQ + r0 + r) * HD + d4 * 4];
  }
  __syncthreads();

  const int rg = t >> 5;   // 0..7 -> rows rg*4 .. rg*4+3
  const int cg = t & 31;   // cols cg, cg+32 within chunk

  // ---- score phase: chunks of 64 slots ----
  for (int j0 = 0; j0 < nslots; j0 += 64) {
    // stage K chunk
#pragma unroll
    for (int l = 0; l < 4; ++l) {
      const int idx = t + l * 256;
      const int kk = idx >> 4, d4 = idx & 15;
      const int c = scol[j0 + kk];
      *(float4*)&ks[kk][d4 * 4] =
          *(const float4*)&k[((size_t)h * SEQ + c) * HD + d4 * 4];
    }
    __syncthreads();

    float acc[4][2];
#pragma unroll
    for (int i = 0; i < 4; ++i) { acc[i][0] = 0.f; acc[i][1] = 0.f; }
#pragma unroll
    for (int d4 = 0; d4 < 16; ++d4) {
      const float4 k0 = *(const float4*)&ks[cg][d4 * 4];
      const float4 k1 = *(const float4*)&ks[cg + 32][d4 * 4];
#pragma unroll
      for (int i = 0; i < 4; ++i) {
        const float4 qv = *(const float4*)&qs[rg * 4 + i][d4 * 4];
        acc[i][0] = fmaf(qv.x, k0.x, acc[i][0]);
        acc[i][0] = fmaf(qv.y, k0.y, acc[i][0]);
        acc[i][0] = fmaf(qv.z, k0.z, acc[i][0]);
        acc[i][0] = fmaf(qv.w, k0.w, acc[i][0]);
        acc[i][1] = fmaf(qv.x, k1.x, acc[i][1]);
        acc[i][1] = fmaf(qv.y, k1.y, acc[i][1]);
        acc[i][1] = fmaf(qv.z, k1.z, acc[i][1]);
        acc[i][1] = fmaf(qv.w, k1.w, acc[i][1]);
      }
    }
    // mask + store to sct
#pragma unroll
    for (int j = 0; j < 2; ++j) {
      const int jslot = j0 + cg + 32 * j;
      const int c = scol[jslot];
      const int mc = scm[jslot];
      const bool glob_slot = (jslot >= blen);
      float s[4];
#pragma unroll
      for (int i = 0; i < 4; ++i) {
        const int row = r0 + rg * 4 + i;
        bool ok;
        if (jslot >= nslots) ok = false;
        else if (!glob_slot) {
          const int dist = row > c ? row - c : c - row;
          ok = (mc != 0) && (dist <= WIN || mc == -1);
        } else {
          ok = (c < lo || c > hi);  // dedupe against tile band
        }
        s[i] = ok ? acc[i][j] : -1e30f;
      }
      *(float4*)&sct[jslot][rg * 4] = make_float4(s[0], s[1], s[2], s[3]);
    }
    __syncthreads();
  }

  // ---- row reductions: max ----
  {
    const int w2 = t >> 5, i = t & 31;
    float m = -1e30f;
    for (int j = w2; j < nslots; j += 8) m = fmaxf(m, sct[j][i]);
    pmax[w2][i] = m;
  }
  __syncthreads();
  if (t < 32) {
    float m = pmax[0][t];
#pragma unroll
    for (int w = 1; w < 8; ++w) m = fmaxf(m, pmax[w][t]);
    rmax[t] = m;
  }
  __syncthreads();
  // ---- exp + sum ----
  {
    const int w2 = t >> 5, i = t & 31;
    const float rm = rmax[i];
    float s = 0.f;
    for (int j = w2; j < nslots; j += 8) {
      const float val = sct[j][i];
      const float pp = (val > -1e29f) ? __expf(val - rm) : 0.0f;
      sct[j][i] = pp;
      s += pp;
    }
    psum[w2][i] = s;
  }
  __syncthreads();
  if (t < 32) {
    float s = psum[0][t];
#pragma unroll
    for (int w = 1; w < 8; ++w) s += psum[w][t];
    rinv[t] = 1.0f / s;
  }
  __syncthreads();

  // ---- attn writes (normal rows only; zeros pre-memset) ----
  {
    const int i = t >> 3, l8 = t & 7;
    if (mrow[i] == 1) {
      float* __restrict__ arow = attn + (size_t)h * SEQ * SEQ + (size_t)(r0 + i) * SEQ;
      const float inv = rinv[i];
      for (int j = l8; j < nslots; j += 8) {
        const float pp = sct[j][i];
        if (pp != 0.0f) arow[scol[j]] = pp * inv;
      }
    }
  }

  // ---- PV phase: chunks of 64 slots, V staged into ks ----
  const int dg = t & 31;  // d = 2dg, 2dg+1
  float ctx0[4] = {0.f, 0.f, 0.f, 0.f};
  float ctx1[4] = {0.f, 0.f, 0.f, 0.f};
  for (int j0 = 0; j0 < nslots; j0 += 64) {
    __syncthreads();  // protect ks from previous use
#pragma unroll
    for (int l = 0; l < 4; ++l) {
      const int idx = t + l * 256;
      const int kk = idx >> 4, d4 = idx & 15;
      const int c = scol[j0 + kk];
      *(float4*)&ks[kk][d4 * 4] =
          *(const float4*)&v[((size_t)h * SEQ + c) * HD + d4 * 4];
    }
    __syncthreads();
    const int jmax = (nslots - j0) < 64 ? (nslots - j0) : 64;
#pragma unroll 4
    for (int jj = 0; jj < jmax; ++jj) {
      const float4 p = *(const float4*)&sct[j0 + jj][rg * 4];
      const float2 vv = *(const float2*)&ks[jj][2 * dg];
      ctx0[0] = fmaf(p.x, vv.x, ctx0[0]);
      ctx1[0] = fmaf(p.x, vv.y, ctx1[0]);
      ctx0[1] = fmaf(p.y, vv.x, ctx0[1]);
      ctx1[1] = fmaf(p.y, vv.y, ctx1[1]);
      ctx0[2] = fmaf(p.z, vv.x, ctx0[2]);
      ctx1[2] = fmaf(p.z, vv.y, ctx1[2]);
      ctx0[3] = fmaf(p.w, vv.x, ctx0[3]);
      ctx1[3] = fmaf(p.w, vv.y, ctx1[3]);
    }
  }
  // ---- out writes ----
#pragma unroll
  for (int i = 0; i < 4; ++i) {
    const int row = rg * 4 + i;
    const int mi = mrow[row];
    if (mi == 1) {
      const float inv = rinv[row];
      float2 o;
      o.x = ctx0[i] * inv;
      o.y = ctx1[i] * inv;
      *(float2*)&out[(size_t)(r0 + row) * DIM + h * HD + 2 * dg] = o;
    } else if (mi == 0) {
      float2 z; z.x = 0.f; z.y = 0.f;
      *(float2*)&out[(size_t)(r0 + row) * DIM + h * HD + 2 * dg] = z;
    }
  }
}

// ------- local-attn probabilities for GLOBAL rows (compact grid, no ctx) -------
__global__ __launch_bounds__(256) void growrow_attn_kernel(
    const float* __restrict__ q, const float* __restrict__ k,
    const int* __restrict__ mask, const int* __restrict__ g,
    float* __restrict__ attn) {
  const int nglob = g[0];
  const int j0 = blockIdx.x >> 3;
  const int h = blockIdx.x & 7;
  const int t = threadIdx.x;

  __shared__ float sc[SEQ];
  __shared__ float qrow[HD];
  __shared__ float red[8];

  for (int jj = j0; jj < nglob; jj += 32) {
    const int i = g[1 + jj];
    __syncthreads();
    if (t < HD) qrow[t] = q[((size_t)h * SEQ + i) * HD + t];
    __syncthreads();

    float lmax = -1e30f;
#pragma unroll 2
    for (int c = t; c < SEQ; c += 256) {
      const bool ok = (mask[c] != 0);
      const float* kr = &k[((size_t)h * SEQ + c) * HD];
      float a0 = 0.f, a1 = 0.f, a2 = 0.f, a3 = 0.f;
#pragma unroll
      for (int d = 0; d < HD; d += 4) {
        const float4 kv = *(const float4*)&kr[d];
        const float4 qv = *(const float4*)&qrow[d];
        a0 = fmaf(qv.x, kv.x, a0);
        a1 = fmaf(qv.y, kv.y, a1);
        a2 = fmaf(qv.z, kv.z, a2);
        a3 = fmaf(qv.w, kv.w, a3);
      }
      const float s = ok ? ((a0 + a1) + (a2 + a3)) : -1e30f;
      lmax = fmaxf(lmax, s);
      sc[c] = s;
    }
    const float wm = wave_max(lmax);
    if ((t & 63) == 0) red[t >> 6] = wm;
    __syncthreads();
    const float rmax = fmaxf(fmaxf(red[0], red[1]), fmaxf(red[2], red[3]));

    float lsum = 0.f;
#pragma unroll 2
    for (int c = t; c < SEQ; c += 256) {
      const float s = sc[c];
      const float pp = (s > -1e29f) ? __expf(s - rmax) : 0.0f;
      sc[c] = pp;
      lsum += pp;
    }
    const float wsum = wave_sum(lsum);
    __syncthreads();
    if ((t & 63) == 0) red[4 + (t >> 6)] = wsum;
    __syncthreads();
    const float rsum = (red[4] + red[5]) + (red[6] + red[7]);
    const float inv = 1.0f / rsum;

    float* __restrict__ arow = attn + (size_t)h * SEQ * SEQ + (size_t)i * SEQ;
#pragma unroll 2
    for (int c = t; c < SEQ; c += 256) {
      const float pp = sc[c];
      if (pp != 0.0f) arow[c] = pp * inv;
    }
  }
}

// ---------------- Global attention branch (compact grid) ----------------
__global__ __launch_bounds__(256) void global_attn_kernel(
    const float* __restrict__ qg, const float* __restrict__ kg,
    const float* __restrict__ vg, const int* __restrict__ mask,
    const int* __restrict__ g, float* __restrict__ out) {
  const int nglob = g[0];
  const int j0 = blockIdx.x >> 3;
  const int h = blockIdx.x & 7;
  const int t = threadIdx.x;

  __shared__ float sc[SEQ];
  __shared__ float qrow[HD];
  __shared__ float red[8];
  __shared__ float ctxp[4][HD];

  for (int jj = j0; jj < nglob; jj += 32) {
    const int i = g[1 + jj];
    __syncthreads();
    if (t < HD) qrow[t] = qg[((size_t)h * SEQ + i) * HD + t];
    __syncthreads();

    float lmax = -1e30f;
#pragma unroll 2
    for (int c = t; c < SEQ; c += 256) {
      const bool ok = (mask[c] != 0);
      const float* kr = &kg[((size_t)h * SEQ + c) * HD];
      float a0 = 0.f, a1 = 0.f, a2 = 0.f, a3 = 0.f;
#pragma unroll
      for (int d = 0; d < HD; d += 4) {
        const float4 kv = *(const float4*)&kr[d];
        const float4 qv = *(const float4*)&qrow[d];
        a0 = fmaf(qv.x, kv.x, a0);
        a1 = fmaf(qv.y, kv.y, a1);
        a2 = fmaf(qv.z, kv.z, a2);
        a3 = fmaf(qv.w, kv.w, a3);
      }
      const float s = ok ? ((a0 + a1) + (a2 + a3)) : -1e30f;
      lmax = fmaxf(lmax, s);
      sc[c] = s;
    }
    const float wm = wave_max(lmax);
    if ((t & 63) == 0) red[t >> 6] = wm;
    __syncthreads();
    const float rmax = fmaxf(fmaxf(red[0], red[1]), fmaxf(red[2], red[3]));

    float lsum = 0.f;
#pragma unroll 2
    for (int c = t; c < SEQ; c += 256) {
      const float s = sc[c];
      const float pp = (s > -1e29f) ? __expf(s - rmax) : 0.0f;
      sc[c] = pp;
      lsum += pp;
    }
    const float wsum = wave_sum(lsum);
    __syncthreads();
    if ((t & 63) == 0) red[4 + (t >> 6)] = wsum;
    __syncthreads();
    const float rsum = (red[4] + red[5]) + (red[6] + red[7]);
    const float inv = 1.0f / rsum;

    const int wv = t >> 6;
    const int d = t & 63;
    float ctx = 0.f;
#pragma unroll 8
    for (int c = wv; c < SEQ; c += 4) {
      ctx = fmaf(sc[c], vg[((size_t)h * SEQ + c) * HD + d], ctx);
    }
    ctxp[wv][d] = ctx;
    __syncthreads();
    if (t < HD) {
      const float r = ((ctxp[0][t] + ctxp[1][t]) + (ctxp[2][t] + ctxp[3][t])) * inv;
      out[(size_t)i * DIM + h * HD + t] = r;
    }
  }
}

// ---------------- host ----------------
extern "C" void kernel_launch(void* const* d_in, const int* in_sizes, int n_in,
                              void* d_out, int out_size, void* d_ws, size_t ws_size,
                              hipStream_t stream) {
  const float* hs = (const float*)d_in[0];
  const int* mask = (const int*)d_in[13];

  float* q  = (float*)d_ws;
  float* kx = q  + (size_t)SEQ * DIM;
  float* vx = kx + (size_t)SEQ * DIM;
  float* qg = vx + (size_t)SEQ * DIM;
  float* kg = qg + (size_t)SEQ * DIM;
  float* vg = kg + (size_t)SEQ * DIM;
  int* gcols = (int*)(vg + (size_t)SEQ * DIM);  // [1 + SEQ]

  float* out  = (float*)d_out;            // [1,S,DIM]
  float* attn = out + (size_t)SEQ * DIM;  // [1,H,S,S]

  hipMemsetAsync(attn, 0, (size_t)HEADS * SEQ * SEQ * sizeof(float), stream);

  hipLaunchKernelGGL(setup_kernel, dim3(1), dim3(256), 0, stream, mask, gcols);

  ProjArgs pa;
  pa.W[0] = (const float*)d_in[1];  pa.b[0] = (const float*)d_in[2];  pa.out[0] = q;
  pa.W[1] = (const float*)d_in[3];  pa.b[1] = (const float*)d_in[4];  pa.out[1] = kx;
  pa.W[2] = (const float*)d_in[5];  pa.b[2] = (const float*)d_in[6];  pa.out[2] = vx;
  pa.W[3] = (const float*)d_in[7];  pa.b[3] = (const float*)d_in[8];  pa.out[3] = qg;
  pa.W[4] = (const float*)d_in[9];  pa.b[4] = (const float*)d_in[10]; pa.out[4] = kg;
  pa.W[5] = (const float*)d_in[11]; pa.b[5] = (const float*)d_in[12]; pa.out[5] = vg;

  dim3 g1(SEQ / 64, DIM / 64, 6);
  hipLaunchKernelGGL(proj_kernel, g1, dim3(256), 0, stream, hs, pa);

  dim3 g2(SEQ / 32, HEADS);
  hipLaunchKernelGGL(local_attn_tile_kernel, g2, dim3(256), 0, stream, q, kx, vx, mask, gcols, out, attn);
  hipLaunchKernelGGL(growrow_attn_kernel, dim3(256), dim3(256), 0, stream, q, kx, mask, gcols, attn);
  hipLaunchKernelGGL(global_attn_kernel, dim3(256), dim3(256), 0, stream, qg, kg, vg, mask, gcols, out);
}

// Round 5
// 201.823 us; speedup vs baseline: 10.6329x; 1.3195x over previous
//
#include <hip/hip_runtime.h>

#define SEQ 2048
#define DIM 512
#define HEADS 8
#define HD 64
#define WIN 128
#define NSMAX 320  // 288 band-union + up to 32 global cols
#define KCAT 1536  // 3x bf16-split K

typedef short bf16x8 __attribute__((ext_vector_type(8)));
typedef float f32x4 __attribute__((ext_vector_type(4)));

__device__ inline unsigned short f2bf(float x) {
  unsigned u = __float_as_uint(x);
  unsigned r = (u + 0x7FFF + ((u >> 16) & 1)) >> 16;  // RTNE (inputs have no NaN/inf)
  return (unsigned short)r;
}
__device__ inline float bf2f(unsigned short s) {
  return __uint_as_float((unsigned)s << 16);
}

// ---------------- convert X -> Xcat = [hi | hi | lo] (2048 x 1536 bf16) -------
__global__ __launch_bounds__(256) void convert_x_kernel(
    const float* __restrict__ X, unsigned short* __restrict__ Xc) {
  const int idx = (blockIdx.x * 256 + threadIdx.x) * 4;  // over 2048*512
  const int m = idx >> 9, k = idx & 511;
  const float4 xv = *(const float4*)&X[idx];
  ushort4 hi, lo;
  hi.x = f2bf(xv.x); lo.x = f2bf(xv.x - bf2f(hi.x));
  hi.y = f2bf(xv.y); lo.y = f2bf(xv.y - bf2f(hi.y));
  hi.z = f2bf(xv.z); lo.z = f2bf(xv.z - bf2f(hi.z));
  hi.w = f2bf(xv.w); lo.w = f2bf(xv.w - bf2f(hi.w));
  unsigned short* row = Xc + (size_t)m * KCAT;
  *(ushort4*)&row[k] = hi;
  *(ushort4*)&row[k + 512] = hi;
  *(ushort4*)&row[k + 1024] = lo;
}

// ---------------- convert W_p -> Wcat_p = [hi | lo | hi] (512 x 1536 bf16) ----
struct WArgs { const float* W[6]; unsigned short* Wc[6]; };
__global__ __launch_bounds__(256) void convert_w_kernel(WArgs a) {
  const int p = blockIdx.y;
  const float* __restrict__ W = a.W[p];
  unsigned short* __restrict__ Wc = a.Wc[p];
  const int idx = (blockIdx.x * 256 + threadIdx.x) * 4;  // over 512*512
  const int n = idx >> 9, k = idx & 511;
  const float4 xv = *(const float4*)&W[idx];
  ushort4 hi, lo;
  hi.x = f2bf(xv.x); lo.x = f2bf(xv.x - bf2f(hi.x));
  hi.y = f2bf(xv.y); lo.y = f2bf(xv.y - bf2f(hi.y));
  hi.z = f2bf(xv.z); lo.z = f2bf(xv.z - bf2f(hi.z));
  hi.w = f2bf(xv.w); lo.w = f2bf(xv.w - bf2f(hi.w));
  unsigned short* row = Wc + (size_t)n * KCAT;
  *(ushort4*)&row[k] = hi;
  *(ushort4*)&row[k + 512] = lo;
  *(ushort4*)&row[k + 1024] = hi;
}

// ---------------- MFMA projection GEMM: out[m][n] = sum_k Xc[m][k]*Wc[n][k] --
// BM=128, BN=64, BK=64; 4 waves; head-major output + bias + scale epilogue.
struct PMArgs { const unsigned short* Wc[6]; const float* b[6]; float* out[6]; };
__global__ __launch_bounds__(256) void proj_mfma_kernel(
    const unsigned short* __restrict__ Xc, PMArgs a) {
  const int p = blockIdx.z;
  const unsigned short* __restrict__ Wc = a.Wc[p];
  const float* __restrict__ bias = a.b[p];
  float* __restrict__ out = a.out[p];
  const float scale = (p == 0 || p == 3) ? 0.125f : 1.0f;

  __shared__ __align__(16) short As[128 * 64];  // [row][chunk^swz], 128B rows
  __shared__ __align__(16) short Bs[64 * 64];

  const int t = threadIdx.x;
  const int w = t >> 6, l = t & 63;
  const int m0 = blockIdx.x * 128, n0 = blockIdx.y * 64;

  f32x4 acc[2][4];
#pragma unroll
  for (int i = 0; i < 2; ++i)
#pragma unroll
    for (int j = 0; j < 4; ++j) acc[i][j] = (f32x4)0.0f;

  for (int k0 = 0; k0 < KCAT; k0 += 64) {
    __syncthreads();
    // stage A: 128 rows x 8 chunks(16B); swizzled slot = ch ^ (row&7)
#pragma unroll
    for (int j = 0; j < 4; ++j) {
      const int idx = t + j * 256;
      const int row = idx >> 3, ch = idx & 7;
      *(int4*)&As[row * 64 + (ch ^ (row & 7)) * 8] =
          *(const int4*)&Xc[(size_t)(m0 + row) * KCAT + k0 + ch * 8];
    }
    // stage B: 64 rows x 8 chunks
#pragma unroll
    for (int j = 0; j < 2; ++j) {
      const int idx = t + j * 256;
      const int row = idx >> 3, ch = idx & 7;
      *(int4*)&Bs[row * 64 + (ch ^ (row & 7)) * 8] =
          *(const int4*)&Wc[(size_t)(n0 + row) * KCAT + k0 + ch * 8];
    }
    __syncthreads();
#pragma unroll
    for (int s = 0; s < 2; ++s) {
      bf16x8 af[2], bfr[4];
#pragma unroll
      for (int fm = 0; fm < 2; ++fm) {
        const int row = w * 32 + fm * 16 + (l & 15);
        const int c = s * 4 + (l >> 4);
        af[fm] = *(const bf16x8*)&As[row * 64 + (c ^ (row & 7)) * 8];
      }
#pragma unroll
      for (int fn = 0; fn < 4; ++fn) {
        const int row = fn * 16 + (l & 15);
        const int c = s * 4 + (l >> 4);
        bfr[fn] = *(const bf16x8*)&Bs[row * 64 + (c ^ (row & 7)) * 8];
      }
#pragma unroll
      for (int fm = 0; fm < 2; ++fm)
#pragma unroll
        for (int fn = 0; fn < 4; ++fn)
          acc[fm][fn] = __builtin_amdgcn_mfma_f32_16x16x32_bf16(
              af[fm], bfr[fn], acc[fm][fn], 0, 0, 0);
    }
  }

  // epilogue: D[(l>>4)*4+r][l&15] -> head-major out + bias, * scale
  const int h = n0 >> 6;
  const int col = l & 15, rb = (l >> 4) * 4;
#pragma unroll
  for (int fn = 0; fn < 4; ++fn) {
    const float bv = bias[n0 + fn * 16 + col];
#pragma unroll
    for (int fm = 0; fm < 2; ++fm) {
#pragma unroll
      for (int r = 0; r < 4; ++r) {
        const int m = m0 + w * 32 + fm * 16 + rb + r;
        out[((size_t)h * SEQ + m) * HD + fn * 16 + col] =
            (acc[fm][fn][r] + bv) * scale;
      }
    }
  }
}

// ---------------- setup: ordered compact list of global columns ----------------
__global__ __launch_bounds__(256) void setup_kernel(const int* __restrict__ mask,
                                                    int* __restrict__ g) {
  __shared__ int wtot[4];
  const int t = threadIdx.x;
  const int lane = t & 63;
  const int wv = t >> 6;
  int loc[8];
  int n = 0;
  const int base = t * 8;
#pragma unroll
  for (int j = 0; j < 8; ++j) {
    const int c = base + j;
    if (mask[c] == -1) loc[n++] = c;
  }
  int x = n;
#pragma unroll
  for (int o = 1; o < 64; o <<= 1) {
    const int y = __shfl_up(x, o);
    if (lane >= o) x += y;
  }
  if (lane == 63) wtot[wv] = x;
  __syncthreads();
  int basew = 0;
  for (int w = 0; w < wv; ++w) basew += wtot[w];
  if (t == 255) g[0] = basew + x;
  const int off = basew + x - n;
  for (int j = 0; j < n; ++j) g[1 + off + j] = loc[j];
}

// ---------------- reduction helpers ----------------
__device__ inline float wave_max(float x) {
#pragma unroll
  for (int o = 32; o > 0; o >>= 1) x = fmaxf(x, __shfl_xor(x, o));
  return x;
}
__device__ inline float wave_sum(float x) {
#pragma unroll
  for (int o = 32; o > 0; o >>= 1) x += __shfl_xor(x, o);
  return x;
}

// ---------------- Tiled local attention: 32 query rows per block ----------------
__global__ __launch_bounds__(256) void local_attn_tile_kernel(
    const float* __restrict__ q, const float* __restrict__ k,
    const float* __restrict__ v, const int* __restrict__ mask,
    const int* __restrict__ g, float* __restrict__ out,
    float* __restrict__ attn) {
  const int h = blockIdx.y;
  const int r0 = blockIdx.x * 32;
  const int t = threadIdx.x;

  __shared__ float qs[32][68];
  __shared__ float ks[64][68];
  __shared__ float sct[NSMAX][36];
  __shared__ int scol[NSMAX];
  __shared__ int scm[NSMAX];
  __shared__ int mrow[32];
  __shared__ float pmax[8][32], psum[8][32];
  __shared__ float rmax[32], rinv[32];

  const int nglob_raw = g[0];
  const int nglob = nglob_raw < 32 ? nglob_raw : 32;
  const int lo = (r0 - WIN) > 0 ? (r0 - WIN) : 0;
  const int hi = (r0 + 31 + WIN) < (SEQ - 1) ? (r0 + 31 + WIN) : (SEQ - 1);
  const int blen = hi - lo + 1;
  const int nslots = blen + nglob;

  if (t < 32) mrow[t] = mask[r0 + t];
  for (int j = t; j < NSMAX; j += 256) {
    int c = 0;
    if (j < blen) c = lo + j;
    else if (j < nslots) c = g[1 + j - blen];
    scol[j] = c;
    scm[j] = mask[c];
  }
#pragma unroll
  for (int l = 0; l < 2; ++l) {
    const int idx = t + l * 256;
    const int r = idx >> 4, d4 = idx & 15;
    *(float4*)&qs[r][d4 * 4] =
        *(const float4*)&q[((size_t)h * SEQ + r0 + r) * HD + d4 * 4];
  }
  __syncthreads();

  const int rg = t >> 5;
  const int cg = t & 31;

  for (int j0 = 0; j0 < nslots; j0 += 64) {
#pragma unroll
    for (int l = 0; l < 4; ++l) {
      const int idx = t + l * 256;
      const int kk = idx >> 4, d4 = idx & 15;
      const int c = scol[j0 + kk];
      *(float4*)&ks[kk][d4 * 4] =
          *(const float4*)&k[((size_t)h * SEQ + c) * HD + d4 * 4];
    }
    __syncthreads();

    float acc[4][2];
#pragma unroll
    for (int i = 0; i < 4; ++i) { acc[i][0] = 0.f; acc[i][1] = 0.f; }
#pragma unroll
    for (int d4 = 0; d4 < 16; ++d4) {
      const float4 k0 = *(const float4*)&ks[cg][d4 * 4];
      const float4 k1 = *(const float4*)&ks[cg + 32][d4 * 4];
#pragma unroll
      for (int i = 0; i < 4; ++i) {
        const float4 qv = *(const float4*)&qs[rg * 4 + i][d4 * 4];
        acc[i][0] = fmaf(qv.x, k0.x, acc[i][0]);
        acc[i][0] = fmaf(qv.y, k0.y, acc[i][0]);
        acc[i][0] = fmaf(qv.z, k0.z, acc[i][0]);
        acc[i][0] = fmaf(qv.w, k0.w, acc[i][0]);
        acc[i][1] = fmaf(qv.x, k1.x, acc[i][1]);
        acc[i][1] = fmaf(qv.y, k1.y, acc[i][1]);
        acc[i][1] = fmaf(qv.z, k1.z, acc[i][1]);
        acc[i][1] = fmaf(qv.w, k1.w, acc[i][1]);
      }
    }
#pragma unroll
    for (int j = 0; j < 2; ++j) {
      const int jslot = j0 + cg + 32 * j;
      const int c = scol[jslot];
      const int mc = scm[jslot];
      const bool glob_slot = (jslot >= blen);
      float s[4];
#pragma unroll
      for (int i = 0; i < 4; ++i) {
        const int row = r0 + rg * 4 + i;
        bool ok;
        if (jslot >= nslots) ok = false;
        else if (!glob_slot) {
          const int dist = row > c ? row - c : c - row;
          ok = (mc != 0) && (dist <= WIN || mc == -1);
        } else {
          ok = (c < lo || c > hi);
        }
        s[i] = ok ? acc[i][j] : -1e30f;
      }
      *(float4*)&sct[jslot][rg * 4] = make_float4(s[0], s[1], s[2], s[3]);
    }
    __syncthreads();
  }

  {
    const int w2 = t >> 5, i = t & 31;
    float m = -1e30f;
    for (int j = w2; j < nslots; j += 8) m = fmaxf(m, sct[j][i]);
    pmax[w2][i] = m;
  }
  __syncthreads();
  if (t < 32) {
    float m = pmax[0][t];
#pragma unroll
    for (int w = 1; w < 8; ++w) m = fmaxf(m, pmax[w][t]);
    rmax[t] = m;
  }
  __syncthreads();
  {
    const int w2 = t >> 5, i = t & 31;
    const float rm = rmax[i];
    float s = 0.f;
    for (int j = w2; j < nslots; j += 8) {
      const float val = sct[j][i];
      const float pp = (val > -1e29f) ? __expf(val - rm) : 0.0f;
      sct[j][i] = pp;
      s += pp;
    }
    psum[w2][i] = s;
  }
  __syncthreads();
  if (t < 32) {
    float s = psum[0][t];
#pragma unroll
    for (int w = 1; w < 8; ++w) s += psum[w][t];
    rinv[t] = 1.0f / s;
  }
  __syncthreads();

  {
    const int i = t >> 3, l8 = t & 7;
    if (mrow[i] == 1) {
      float* __restrict__ arow = attn + (size_t)h * SEQ * SEQ + (size_t)(r0 + i) * SEQ;
      const float inv = rinv[i];
      for (int j = l8; j < nslots; j += 8) {
        const float pp = sct[j][i];
        if (pp != 0.0f) arow[scol[j]] = pp * inv;
      }
    }
  }

  const int dg = t & 31;
  float ctx0[4] = {0.f, 0.f, 0.f, 0.f};
  float ctx1[4] = {0.f, 0.f, 0.f, 0.f};
  for (int j0 = 0; j0 < nslots; j0 += 64) {
    __syncthreads();
#pragma unroll
    for (int l = 0; l < 4; ++l) {
      const int idx = t + l * 256;
      const int kk = idx >> 4, d4 = idx & 15;
      const int c = scol[j0 + kk];
      *(float4*)&ks[kk][d4 * 4] =
          *(const float4*)&v[((size_t)h * SEQ + c) * HD + d4 * 4];
    }
    __syncthreads();
    const int jmax = (nslots - j0) < 64 ? (nslots - j0) : 64;
#pragma unroll 4
    for (int jj = 0; jj < jmax; ++jj) {
      const float4 p = *(const float4*)&sct[j0 + jj][rg * 4];
      const float2 vv = *(const float2*)&ks[jj][2 * dg];
      ctx0[0] = fmaf(p.x, vv.x, ctx0[0]);
      ctx1[0] = fmaf(p.x, vv.y, ctx1[0]);
      ctx0[1] = fmaf(p.y, vv.x, ctx0[1]);
      ctx1[1] = fmaf(p.y, vv.y, ctx1[1]);
      ctx0[2] = fmaf(p.z, vv.x, ctx0[2]);
      ctx1[2] = fmaf(p.z, vv.y, ctx1[2]);
      ctx0[3] = fmaf(p.w, vv.x, ctx0[3]);
      ctx1[3] = fmaf(p.w, vv.y, ctx1[3]);
    }
  }
#pragma unroll
  for (int i = 0; i < 4; ++i) {
    const int row = rg * 4 + i;
    const int mi = mrow[row];
    if (mi == 1) {
      const float inv = rinv[row];
      float2 o;
      o.x = ctx0[i] * inv;
      o.y = ctx1[i] * inv;
      *(float2*)&out[(size_t)(r0 + row) * DIM + h * HD + 2 * dg] = o;
    } else if (mi == 0) {
      float2 z; z.x = 0.f; z.y = 0.f;
      *(float2*)&out[(size_t)(r0 + row) * DIM + h * HD + 2 * dg] = z;
    }
  }
}

// ------- local-attn probabilities for GLOBAL rows (compact grid, no ctx) -------
__global__ __launch_bounds__(256) void growrow_attn_kernel(
    const float* __restrict__ q, const float* __restrict__ k,
    const int* __restrict__ mask, const int* __restrict__ g,
    float* __restrict__ attn) {
  const int nglob = g[0];
  const int j0 = blockIdx.x >> 3;
  const int h = blockIdx.x & 7;
  const int t = threadIdx.x;

  __shared__ float sc[SEQ];
  __shared__ float qrow[HD];
  __shared__ float red[8];

  for (int jj = j0; jj < nglob; jj += 32) {
    const int i = g[1 + jj];
    __syncthreads();
    if (t < HD) qrow[t] = q[((size_t)h * SEQ + i) * HD + t];
    __syncthreads();

    float lmax = -1e30f;
#pragma unroll 2
    for (int c = t; c < SEQ; c += 256) {
      const bool ok = (mask[c] != 0);
      const float* kr = &k[((size_t)h * SEQ + c) * HD];
      float a0 = 0.f, a1 = 0.f, a2 = 0.f, a3 = 0.f;
#pragma unroll
      for (int d = 0; d < HD; d += 4) {
        const float4 kv = *(const float4*)&kr[d];
        const float4 qv = *(const float4*)&qrow[d];
        a0 = fmaf(qv.x, kv.x, a0);
        a1 = fmaf(qv.y, kv.y, a1);
        a2 = fmaf(qv.z, kv.z, a2);
        a3 = fmaf(qv.w, kv.w, a3);
      }
      const float s = ok ? ((a0 + a1) + (a2 + a3)) : -1e30f;
      lmax = fmaxf(lmax, s);
      sc[c] = s;
    }
    const float wm = wave_max(lmax);
    if ((t & 63) == 0) red[t >> 6] = wm;
    __syncthreads();
    const float rmax = fmaxf(fmaxf(red[0], red[1]), fmaxf(red[2], red[3]));

    float lsum = 0.f;
#pragma unroll 2
    for (int c = t; c < SEQ; c += 256) {
      const float s = sc[c];
      const float pp = (s > -1e29f) ? __expf(s - rmax) : 0.0f;
      sc[c] = pp;
      lsum += pp;
    }
    const float wsum = wave_sum(lsum);
    __syncthreads();
    if ((t & 63) == 0) red[4 + (t >> 6)] = wsum;
    __syncthreads();
    const float rsum = (red[4] + red[5]) + (red[6] + red[7]);
    const float inv = 1.0f / rsum;

    float* __restrict__ arow = attn + (size_t)h * SEQ * SEQ + (size_t)i * SEQ;
#pragma unroll 2
    for (int c = t; c < SEQ; c += 256) {
      const float pp = sc[c];
      if (pp != 0.0f) arow[c] = pp * inv;
    }
  }
}

// ---------------- Global attention branch (compact grid) ----------------
__global__ __launch_bounds__(256) void global_attn_kernel(
    const float* __restrict__ qg, const float* __restrict__ kg,
    const float* __restrict__ vg, const int* __restrict__ mask,
    const int* __restrict__ g, float* __restrict__ out) {
  const int nglob = g[0];
  const int j0 = blockIdx.x >> 3;
  const int h = blockIdx.x & 7;
  const int t = threadIdx.x;

  __shared__ float sc[SEQ];
  __shared__ float qrow[HD];
  __shared__ float red[8];
  __shared__ float ctxp[4][HD];

  for (int jj = j0; jj < nglob; jj += 32) {
    const int i = g[1 + jj];
    __syncthreads();
    if (t < HD) qrow[t] = qg[((size_t)h * SEQ + i) * HD + t];
    __syncthreads();

    float lmax = -1e30f;
#pragma unroll 2
    for (int c = t; c < SEQ; c += 256) {
      const bool ok = (mask[c] != 0);
      const float* kr = &kg[((size_t)h * SEQ + c) * HD];
      float a0 = 0.f, a1 = 0.f, a2 = 0.f, a3 = 0.f;
#pragma unroll
      for (int d = 0; d < HD; d += 4) {
        const float4 kv = *(const float4*)&kr[d];
        const float4 qv = *(const float4*)&qrow[d];
        a0 = fmaf(qv.x, kv.x, a0);
        a1 = fmaf(qv.y, kv.y, a1);
        a2 = fmaf(qv.z, kv.z, a2);
        a3 = fmaf(qv.w, kv.w, a3);
      }
      const float s = ok ? ((a0 + a1) + (a2 + a3)) : -1e30f;
      lmax = fmaxf(lmax, s);
      sc[c] = s;
    }
    const float wm = wave_max(lmax);
    if ((t & 63) == 0) red[t >> 6] = wm;
    __syncthreads();
    const float rmax = fmaxf(fmaxf(red[0], red[1]), fmaxf(red[2], red[3]));

    float lsum = 0.f;
#pragma unroll 2
    for (int c = t; c < SEQ; c += 256) {
      const float s = sc[c];
      const float pp = (s > -1e29f) ? __expf(s - rmax) : 0.0f;
      sc[c] = pp;
      lsum += pp;
    }
    const float wsum = wave_sum(lsum);
    __syncthreads();
    if ((t & 63) == 0) red[4 + (t >> 6)] = wsum;
    __syncthreads();
    const float rsum = (red[4] + red[5]) + (red[6] + red[7]);
    const float inv = 1.0f / rsum;

    const int wv = t >> 6;
    const int d = t & 63;
    float ctx = 0.f;
#pragma unroll 8
    for (int c = wv; c < SEQ; c += 4) {
      ctx = fmaf(sc[c], vg[((size_t)h * SEQ + c) * HD + d], ctx);
    }
    ctxp[wv][d] = ctx;
    __syncthreads();
    if (t < HD) {
      const float r = ((ctxp[0][t] + ctxp[1][t]) + (ctxp[2][t] + ctxp[3][t])) * inv;
      out[(size_t)i * DIM + h * HD + t] = r;
    }
  }
}

// ---------------- host ----------------
extern "C" void kernel_launch(void* const* d_in, const int* in_sizes, int n_in,
                              void* d_out, int out_size, void* d_ws, size_t ws_size,
                              hipStream_t stream) {
  const float* hs = (const float*)d_in[0];
  const int* mask = (const int*)d_in[13];

  float* q  = (float*)d_ws;                      // 6 x 4MB head-major projections
  float* kx = q  + (size_t)SEQ * DIM;
  float* vx = kx + (size_t)SEQ * DIM;
  float* qg = vx + (size_t)SEQ * DIM;
  float* kg = qg + (size_t)SEQ * DIM;
  float* vg = kg + (size_t)SEQ * DIM;
  int* gcols = (int*)(vg + (size_t)SEQ * DIM);   // [1+SEQ] ints (16KB reserved)
  unsigned short* Xcat = (unsigned short*)((char*)gcols + 16384);  // 6MB
  unsigned short* Wcat0 = Xcat + (size_t)SEQ * KCAT;               // 6 x 1.5MB

  float* out  = (float*)d_out;            // [1,S,DIM]
  float* attn = out + (size_t)SEQ * DIM;  // [1,H,S,S]

  hipMemsetAsync(attn, 0, (size_t)HEADS * SEQ * SEQ * sizeof(float), stream);

  hipLaunchKernelGGL(setup_kernel, dim3(1), dim3(256), 0, stream, mask, gcols);
  hipLaunchKernelGGL(convert_x_kernel, dim3(SEQ * DIM / 1024), dim3(256), 0, stream,
                     hs, Xcat);

  WArgs wa;
  PMArgs pm;
  float* pouts[6] = {q, kx, vx, qg, kg, vg};
  for (int p = 0; p < 6; ++p) {
    wa.W[p] = (const float*)d_in[1 + 2 * p];
    wa.Wc[p] = Wcat0 + (size_t)p * DIM * KCAT;
    pm.Wc[p] = wa.Wc[p];
    pm.b[p] = (const float*)d_in[2 + 2 * p];
    pm.out[p] = pouts[p];
  }
  hipLaunchKernelGGL(convert_w_kernel, dim3(DIM * DIM / 1024, 6), dim3(256), 0,
                     stream, wa);

  dim3 g1(SEQ / 128, DIM / 64, 6);
  hipLaunchKernelGGL(proj_mfma_kernel, g1, dim3(256), 0, stream, Xcat, pm);

  dim3 g2(SEQ / 32, HEADS);
  hipLaunchKernelGGL(local_attn_tile_kernel, g2, dim3(256), 0, stream, q, kx, vx,
                     mask, gcols, out, attn);
  hipLaunchKernelGGL(growrow_attn_kernel, dim3(256), dim3(256), 0, stream, q, kx,
                     mask, gcols, attn);
  hipLaunchKernelGGL(global_attn_kernel, dim3(256), dim3(256), 0, stream, qg, kg,
                     vg, mask, gcols, out);
}

// Round 6
// 163.876 us; speedup vs baseline: 13.0951x; 1.2316x over previous
//
#include <hip/hip_runtime.h>

#define SEQ 2048
#define DIM 512
#define HEADS 8
#define HD 64
#define WIN 128
#define NSMAX 320  // 273 band-union + up to 32 global cols + pad
#define KCAT 1536  // 3x bf16-split K
#define QR 16      // query rows per local-attn block

typedef short bf16x8 __attribute__((ext_vector_type(8)));
typedef float f32x4 __attribute__((ext_vector_type(4)));

__device__ inline unsigned short f2bf(float x) {
  unsigned u = __float_as_uint(x);
  unsigned r = (u + 0x7FFF + ((u >> 16) & 1)) >> 16;  // RTNE
  return (unsigned short)r;
}
__device__ inline float bf2f(unsigned short s) {
  return __uint_as_float((unsigned)s << 16);
}

// ---------------- convert X -> Xcat = [hi | hi | lo] (2048 x 1536 bf16) -------
__global__ __launch_bounds__(256) void convert_x_kernel(
    const float* __restrict__ X, unsigned short* __restrict__ Xc) {
  const int idx = (blockIdx.x * 256 + threadIdx.x) * 4;
  const int m = idx >> 9, k = idx & 511;
  const float4 xv = *(const float4*)&X[idx];
  ushort4 hi, lo;
  hi.x = f2bf(xv.x); lo.x = f2bf(xv.x - bf2f(hi.x));
  hi.y = f2bf(xv.y); lo.y = f2bf(xv.y - bf2f(hi.y));
  hi.z = f2bf(xv.z); lo.z = f2bf(xv.z - bf2f(hi.z));
  hi.w = f2bf(xv.w); lo.w = f2bf(xv.w - bf2f(hi.w));
  unsigned short* row = Xc + (size_t)m * KCAT;
  *(ushort4*)&row[k] = hi;
  *(ushort4*)&row[k + 512] = hi;
  *(ushort4*)&row[k + 1024] = lo;
}

// ---------------- convert W_p -> Wcat_p = [hi | lo | hi] (512 x 1536 bf16) ----
struct WArgs { const float* W[6]; unsigned short* Wc[6]; };
__global__ __launch_bounds__(256) void convert_w_kernel(WArgs a) {
  const int p = blockIdx.y;
  const float* __restrict__ W = a.W[p];
  unsigned short* __restrict__ Wc = a.Wc[p];
  const int idx = (blockIdx.x * 256 + threadIdx.x) * 4;
  const int n = idx >> 9, k = idx & 511;
  const float4 xv = *(const float4*)&W[idx];
  ushort4 hi, lo;
  hi.x = f2bf(xv.x); lo.x = f2bf(xv.x - bf2f(hi.x));
  hi.y = f2bf(xv.y); lo.y = f2bf(xv.y - bf2f(hi.y));
  hi.z = f2bf(xv.z); lo.z = f2bf(xv.z - bf2f(hi.z));
  hi.w = f2bf(xv.w); lo.w = f2bf(xv.w - bf2f(hi.w));
  unsigned short* row = Wc + (size_t)n * KCAT;
  *(ushort4*)&row[k] = hi;
  *(ushort4*)&row[k + 512] = lo;
  *(ushort4*)&row[k + 1024] = hi;
}

// ---------------- MFMA projection GEMM + bf16 dual-write epilogue ------------
struct PMArgs {
  const unsigned short* Wc[6];
  const float* b[6];
  float* out[6];
  unsigned short* outb[6];  // bf16 copies (q,k,v only; else null)
};
__global__ __launch_bounds__(256) void proj_mfma_kernel(
    const unsigned short* __restrict__ Xc, PMArgs a) {
  const int p = blockIdx.z;
  const unsigned short* __restrict__ Wc = a.Wc[p];
  const float* __restrict__ bias = a.b[p];
  float* __restrict__ out = a.out[p];
  unsigned short* __restrict__ outb = a.outb[p];
  const float scale = (p == 0 || p == 3) ? 0.125f : 1.0f;

  __shared__ __align__(16) short As[128 * 64];
  __shared__ __align__(16) short Bs[64 * 64];

  const int t = threadIdx.x;
  const int w = t >> 6, l = t & 63;
  const int m0 = blockIdx.x * 128, n0 = blockIdx.y * 64;

  f32x4 acc[2][4];
#pragma unroll
  for (int i = 0; i < 2; ++i)
#pragma unroll
    for (int j = 0; j < 4; ++j) acc[i][j] = (f32x4)0.0f;

  for (int k0 = 0; k0 < KCAT; k0 += 64) {
    __syncthreads();
#pragma unroll
    for (int j = 0; j < 4; ++j) {
      const int idx = t + j * 256;
      const int row = idx >> 3, ch = idx & 7;
      *(int4*)&As[row * 64 + (ch ^ (row & 7)) * 8] =
          *(const int4*)&Xc[(size_t)(m0 + row) * KCAT + k0 + ch * 8];
    }
#pragma unroll
    for (int j = 0; j < 2; ++j) {
      const int idx = t + j * 256;
      const int row = idx >> 3, ch = idx & 7;
      *(int4*)&Bs[row * 64 + (ch ^ (row & 7)) * 8] =
          *(const int4*)&Wc[(size_t)(n0 + row) * KCAT + k0 + ch * 8];
    }
    __syncthreads();
#pragma unroll
    for (int s = 0; s < 2; ++s) {
      bf16x8 af[2], bfr[4];
#pragma unroll
      for (int fm = 0; fm < 2; ++fm) {
        const int row = w * 32 + fm * 16 + (l & 15);
        const int c = s * 4 + (l >> 4);
        af[fm] = *(const bf16x8*)&As[row * 64 + (c ^ (row & 7)) * 8];
      }
#pragma unroll
      for (int fn = 0; fn < 4; ++fn) {
        const int row = fn * 16 + (l & 15);
        const int c = s * 4 + (l >> 4);
        bfr[fn] = *(const bf16x8*)&Bs[row * 64 + (c ^ (row & 7)) * 8];
      }
#pragma unroll
      for (int fm = 0; fm < 2; ++fm)
#pragma unroll
        for (int fn = 0; fn < 4; ++fn)
          acc[fm][fn] = __builtin_amdgcn_mfma_f32_16x16x32_bf16(
              af[fm], bfr[fn], acc[fm][fn], 0, 0, 0);
    }
  }

  const int h = n0 >> 6;
  const int col = l & 15, rb = (l >> 4) * 4;
#pragma unroll
  for (int fn = 0; fn < 4; ++fn) {
    const float bv = bias[n0 + fn * 16 + col];
#pragma unroll
    for (int fm = 0; fm < 2; ++fm) {
#pragma unroll
      for (int r = 0; r < 4; ++r) {
        const int m = m0 + w * 32 + fm * 16 + rb + r;
        const size_t oi = ((size_t)h * SEQ + m) * HD + fn * 16 + col;
        const float val = (acc[fm][fn][r] + bv) * scale;
        out[oi] = val;
        if (outb) outb[oi] = f2bf(val);
      }
    }
  }
}

// ---------------- setup: ordered compact list of global columns ----------------
__global__ __launch_bounds__(256) void setup_kernel(const int* __restrict__ mask,
                                                    int* __restrict__ g) {
  __shared__ int wtot[4];
  const int t = threadIdx.x;
  const int lane = t & 63;
  const int wv = t >> 6;
  int loc[8];
  int n = 0;
  const int base = t * 8;
#pragma unroll
  for (int j = 0; j < 8; ++j) {
    const int c = base + j;
    if (mask[c] == -1) loc[n++] = c;
  }
  int x = n;
#pragma unroll
  for (int o = 1; o < 64; o <<= 1) {
    const int y = __shfl_up(x, o);
    if (lane >= o) x += y;
  }
  if (lane == 63) wtot[wv] = x;
  __syncthreads();
  int basew = 0;
  for (int w = 0; w < wv; ++w) basew += wtot[w];
  if (t == 255) g[0] = basew + x;
  const int off = basew + x - n;
  for (int j = 0; j < n; ++j) g[1 + off + j] = loc[j];
}

// ---------------- reduction helpers ----------------
__device__ inline float wave_max(float x) {
#pragma unroll
  for (int o = 32; o > 0; o >>= 1) x = fmaxf(x, __shfl_xor(x, o));
  return x;
}
__device__ inline float wave_sum(float x) {
#pragma unroll
  for (int o = 32; o > 0; o >>= 1) x += __shfl_xor(x, o);
  return x;
}

// ---------------- MFMA local attention: 16 rows/block, dense attn writes -----
__global__ __launch_bounds__(256) void local_attn_tile_kernel(
    const unsigned short* __restrict__ qb, const unsigned short* __restrict__ kb,
    const unsigned short* __restrict__ vb, const int* __restrict__ mask,
    const int* __restrict__ g, float* __restrict__ out,
    float* __restrict__ attn) {
  const int h = blockIdx.y;
  const int r0 = blockIdx.x * QR;
  const int t = threadIdx.x;
  const int w = t >> 6, l = t & 63;
  const int g4 = l >> 4;

  __shared__ __align__(16) unsigned short qs[QR * 64];     // swizzled Q, 2KB
  __shared__ __align__(16) unsigned short ks[64 * 64];     // K chunk / V^T chunk, 8KB
  __shared__ __align__(16) unsigned short pbf[QR * NSMAX]; // P bf16 swizzled, 10KB
  __shared__ int scol[NSMAX];
  __shared__ int scm[NSMAX];
  __shared__ int mrow[QR];
  __shared__ float pmax[4][QR], psum[4][QR];
  __shared__ float rmaxs[QR], rinvs[QR];

  const int nglob_raw = g[0];
  const int nglob = nglob_raw < 32 ? nglob_raw : 32;
  const int lo = (r0 - WIN) > 0 ? (r0 - WIN) : 0;
  const int hi = (r0 + QR - 1 + WIN) < (SEQ - 1) ? (r0 + QR - 1 + WIN) : (SEQ - 1);
  const int blen = hi - lo + 1;
  const int nslots = blen + nglob;

  if (t < QR) mrow[t] = mask[r0 + t];
  for (int j = t; j < NSMAX; j += 256) {
    int c = lo;
    if (j < blen) c = lo + j;
    else if (j < nslots) c = g[1 + j - blen];
    scol[j] = c;
    scm[j] = mask[c];
  }
  // Q stage: QR*8 = 128 16B chunks
  if (t < 128) {
    const int row = t >> 3, ch = t & 7;
    *(int4*)&qs[row * 64 + ((ch ^ (row & 7)) << 3)] =
        *(const int4*)&qb[((size_t)h * SEQ + r0 + row) * HD + ch * 8];
  }

  // ---- score phase: 5 chunks of 64 slots, MFMA 16x16x32 ----
  f32x4 acc[5];
#pragma unroll
  for (int c = 0; c < 5; ++c) acc[c] = (f32x4)0.0f;

#pragma unroll
  for (int c = 0; c < 5; ++c) {
    __syncthreads();
    const int j0 = c * 64;
#pragma unroll
    for (int l2 = 0; l2 < 2; ++l2) {
      const int idx = t + l2 * 256;
      const int sl = idx >> 3, ch = idx & 7;
      const int cc = scol[j0 + sl];
      *(int4*)&ks[sl * 64 + ((ch ^ (sl & 7)) << 3)] =
          *(const int4*)&kb[((size_t)h * SEQ + cc) * HD + ch * 8];
    }
    __syncthreads();
    const int rA = l & 15;
    const int slB = w * 16 + (l & 15);
#pragma unroll
    for (int s = 0; s < 2; ++s) {
      const int kc = s * 4 + g4;
      const bf16x8 af = *(const bf16x8*)&qs[rA * 64 + ((kc ^ (rA & 7)) << 3)];
      const bf16x8 bf = *(const bf16x8*)&ks[slB * 64 + ((kc ^ (slB & 7)) << 3)];
      acc[c] = __builtin_amdgcn_mfma_f32_16x16x32_bf16(af, bf, acc[c], 0, 0, 0);
    }
  }

  // ---- mask + row max ----
  float pmx[4] = {-3e30f, -3e30f, -3e30f, -3e30f};
#pragma unroll
  for (int c = 0; c < 5; ++c) {
    const int n = 64 * c + 16 * w + (l & 15);
    const int cc = scol[n], mc = scm[n];
    const bool gl = (n >= blen);
#pragma unroll
    for (int r = 0; r < 4; ++r) {
      const int m = r0 + g4 * 4 + r;
      bool ok;
      if (!gl) {
        const int dist = m > cc ? m - cc : cc - m;
        ok = (mc != 0) && (dist <= WIN || mc == -1);
      } else {
        ok = (n < nslots) && (cc < lo || cc > hi);
      }
      const float s = ok ? acc[c][r] : -1e30f;
      acc[c][r] = s;
      pmx[r] = fmaxf(pmx[r], s);
    }
  }
#pragma unroll
  for (int off = 1; off < 16; off <<= 1)
#pragma unroll
    for (int r = 0; r < 4; ++r) pmx[r] = fmaxf(pmx[r], __shfl_xor(pmx[r], off));
  if ((l & 15) == 0)
#pragma unroll
    for (int r = 0; r < 4; ++r) pmax[w][g4 * 4 + r] = pmx[r];
  __syncthreads();
  if (t < QR)
    rmaxs[t] = fmaxf(fmaxf(pmax[0][t], pmax[1][t]), fmaxf(pmax[2][t], pmax[3][t]));
  __syncthreads();

  // ---- exp + row sum + P->bf16 LDS ----
  float rmx[4], psm[4] = {0.f, 0.f, 0.f, 0.f};
#pragma unroll
  for (int r = 0; r < 4; ++r) rmx[r] = rmaxs[g4 * 4 + r];
#pragma unroll
  for (int c = 0; c < 5; ++c)
#pragma unroll
    for (int r = 0; r < 4; ++r) {
      const float s = acc[c][r];
      const float p = (s > -1e29f) ? __expf(s - rmx[r]) : 0.0f;
      acc[c][r] = p;
      psm[r] += p;
    }
#pragma unroll
  for (int off = 1; off < 16; off <<= 1)
#pragma unroll
    for (int r = 0; r < 4; ++r) psm[r] += __shfl_xor(psm[r], off);
  if ((l & 15) == 0)
#pragma unroll
    for (int r = 0; r < 4; ++r) psum[w][g4 * 4 + r] = psm[r];
#pragma unroll
  for (int c = 0; c < 5; ++c) {
    const int n = 64 * c + 16 * w + (l & 15);
#pragma unroll
    for (int r = 0; r < 4; ++r) {
      const int m = g4 * 4 + r;
      pbf[m * NSMAX + (((n >> 3) ^ (m & 7)) << 3) + (n & 7)] = f2bf(acc[c][r]);
    }
  }
  __syncthreads();
  if (t < QR) rinvs[t] = 1.0f / (psum[0][t] + psum[1][t] + psum[2][t] + psum[3][t]);
  __syncthreads();

  // ---- dense attn zero-fill (outside band; full row for non-normal rows) ----
  {
    const int row = t >> 4, l16 = t & 15;
    const int mi = mrow[row];
    float* __restrict__ arow =
        attn + (size_t)h * SEQ * SEQ + (size_t)(r0 + row) * SEQ;
    const float4 z4 = make_float4(0.f, 0.f, 0.f, 0.f);
    const int lof4 = lo >> 2, hif4 = (hi + 1) >> 2;
    for (int f = l16; f < lof4; f += 16) *(float4*)&arow[f * 4] = z4;
    for (int f = hif4 + l16; f < 512; f += 16) *(float4*)&arow[f * 4] = z4;
    if (mi != 1)
      for (int f = lof4 + l16; f < hif4; f += 16) *(float4*)&arow[f * 4] = z4;
  }
  __syncthreads();  // zeros land before p-stores (glob cols overlap zero region)

  // ---- p-stores from registers (normal rows only) ----
#pragma unroll
  for (int c = 0; c < 5; ++c) {
    const int n = 64 * c + 16 * w + (l & 15);
    const int cc = scol[n];
    const bool gl = (n >= blen);
    const bool gok = gl && (n < nslots) && (cc < lo || cc > hi);
#pragma unroll
    for (int r = 0; r < 4; ++r) {
      const int m = g4 * 4 + r;
      if (mrow[m] == 1 && (!gl || gok))
        attn[(size_t)h * SEQ * SEQ + (size_t)(r0 + m) * SEQ + cc] =
            acc[c][r] * rinvs[m];
    }
  }

  // ---- PV phase: 5 chunks; V^T staged transposed+swizzled into ks ----
  f32x4 cacc = (f32x4)0.0f;
#pragma unroll
  for (int c = 0; c < 5; ++c) {
    __syncthreads();
    const int j0 = c * 64;
    {
      const int sl = t & 63;
      const int cc = scol[j0 + sl];
#pragma unroll
      for (int l2 = 0; l2 < 4; ++l2) {
        const int d4 = (t >> 6) + l2 * 4;
        const ushort4 vv = *(const ushort4*)&vb[((size_t)h * SEQ + cc) * HD + d4 * 4];
#pragma unroll
        for (int e = 0; e < 4; ++e) {
          const int d = d4 * 4 + e;
          ks[d * 64 + (((sl >> 3) ^ (d & 7)) << 3) + (sl & 7)] =
              ((const unsigned short*)&vv)[e];
        }
      }
    }
    __syncthreads();
    const int rA = l & 15;
    const int dB = w * 16 + (l & 15);
#pragma unroll
    for (int s = 0; s < 2; ++s) {
      const int pc = c * 8 + s * 4 + g4;  // pbf slot-chunk
      const int kc = s * 4 + g4;          // vsT slot-chunk
      const bf16x8 af = *(const bf16x8*)&pbf[rA * NSMAX + ((pc ^ (rA & 7)) << 3)];
      const bf16x8 bf = *(const bf16x8*)&ks[dB * 64 + ((kc ^ (dB & 7)) << 3)];
      cacc = __builtin_amdgcn_mfma_f32_16x16x32_bf16(af, bf, cacc, 0, 0, 0);
    }
  }

  // ---- out epilogue ----
  {
    const int d = w * 16 + (l & 15);
#pragma unroll
    for (int r = 0; r < 4; ++r) {
      const int m = g4 * 4 + r;
      const int mi = mrow[m];
      const float val = (mi == 0) ? 0.f : cacc[r] * rinvs[m];
      out[(size_t)(r0 + m) * DIM + h * HD + d] = val;
    }
  }
}

// ------- local-attn probabilities for GLOBAL rows (compact grid, no ctx) -------
__global__ __launch_bounds__(256) void growrow_attn_kernel(
    const float* __restrict__ q, const float* __restrict__ k,
    const int* __restrict__ mask, const int* __restrict__ g,
    float* __restrict__ attn) {
  const int nglob = g[0];
  const int j0 = blockIdx.x >> 3;
  const int h = blockIdx.x & 7;
  const int t = threadIdx.x;

  __shared__ float sc[SEQ];
  __shared__ float qrow[HD];
  __shared__ float red[8];

  for (int jj = j0; jj < nglob; jj += 32) {
    const int i = g[1 + jj];
    __syncthreads();
    if (t < HD) qrow[t] = q[((size_t)h * SEQ + i) * HD + t];
    __syncthreads();

    float lmax = -1e30f;
#pragma unroll 2
    for (int c = t; c < SEQ; c += 256) {
      const bool ok = (mask[c] != 0);
      const float* kr = &k[((size_t)h * SEQ + c) * HD];
      float a0 = 0.f, a1 = 0.f, a2 = 0.f, a3 = 0.f;
#pragma unroll
      for (int d = 0; d < HD; d += 4) {
        const float4 kv = *(const float4*)&kr[d];
        const float4 qv = *(const float4*)&qrow[d];
        a0 = fmaf(qv.x, kv.x, a0);
        a1 = fmaf(qv.y, kv.y, a1);
        a2 = fmaf(qv.z, kv.z, a2);
        a3 = fmaf(qv.w, kv.w, a3);
      }
      const float s = ok ? ((a0 + a1) + (a2 + a3)) : -1e30f;
      lmax = fmaxf(lmax, s);
      sc[c] = s;
    }
    const float wm = wave_max(lmax);
    if ((t & 63) == 0) red[t >> 6] = wm;
    __syncthreads();
    const float rmax = fmaxf(fmaxf(red[0], red[1]), fmaxf(red[2], red[3]));

    float lsum = 0.f;
#pragma unroll 2
    for (int c = t; c < SEQ; c += 256) {
      const float s = sc[c];
      const float pp = (s > -1e29f) ? __expf(s - rmax) : 0.0f;
      sc[c] = pp;
      lsum += pp;
    }
    const float wsum = wave_sum(lsum);
    __syncthreads();
    if ((t & 63) == 0) red[4 + (t >> 6)] = wsum;
    __syncthreads();
    const float rsum = (red[4] + red[5]) + (red[6] + red[7]);
    const float inv = 1.0f / rsum;

    float* __restrict__ arow = attn + (size_t)h * SEQ * SEQ + (size_t)i * SEQ;
#pragma unroll 2
    for (int c = t; c < SEQ; c += 256) {
      const float pp = sc[c];
      if (pp != 0.0f) arow[c] = pp * inv;
    }
  }
}

// ---------------- Global attention branch (compact grid) ----------------
__global__ __launch_bounds__(256) void global_attn_kernel(
    const float* __restrict__ qg, const float* __restrict__ kg,
    const float* __restrict__ vg, const int* __restrict__ mask,
    const int* __restrict__ g, float* __restrict__ out) {
  const int nglob = g[0];
  const int j0 = blockIdx.x >> 3;
  const int h = blockIdx.x & 7;
  const int t = threadIdx.x;

  __shared__ float sc[SEQ];
  __shared__ float qrow[HD];
  __shared__ float red[8];
  __shared__ float ctxp[4][HD];

  for (int jj = j0; jj < nglob; jj += 32) {
    const int i = g[1 + jj];
    __syncthreads();
    if (t < HD) qrow[t] = qg[((size_t)h * SEQ + i) * HD + t];
    __syncthreads();

    float lmax = -1e30f;
#pragma unroll 2
    for (int c = t; c < SEQ; c += 256) {
      const bool ok = (mask[c] != 0);
      const float* kr = &kg[((size_t)h * SEQ + c) * HD];
      float a0 = 0.f, a1 = 0.f, a2 = 0.f, a3 = 0.f;
#pragma unroll
      for (int d = 0; d < HD; d += 4) {
        const float4 kv = *(const float4*)&kr[d];
        const float4 qv = *(const float4*)&qrow[d];
        a0 = fmaf(qv.x, kv.x, a0);
        a1 = fmaf(qv.y, kv.y, a1);
        a2 = fmaf(qv.z, kv.z, a2);
        a3 = fmaf(qv.w, kv.w, a3);
      }
      const float s = ok ? ((a0 + a1) + (a2 + a3)) : -1e30f;
      lmax = fmaxf(lmax, s);
      sc[c] = s;
    }
    const float wm = wave_max(lmax);
    if ((t & 63) == 0) red[t >> 6] = wm;
    __syncthreads();
    const float rmax = fmaxf(fmaxf(red[0], red[1]), fmaxf(red[2], red[3]));

    float lsum = 0.f;
#pragma unroll 2
    for (int c = t; c < SEQ; c += 256) {
      const float s = sc[c];
      const float pp = (s > -1e29f) ? __expf(s - rmax) : 0.0f;
      sc[c] = pp;
      lsum += pp;
    }
    const float wsum = wave_sum(lsum);
    __syncthreads();
    if ((t & 63) == 0) red[4 + (t >> 6)] = wsum;
    __syncthreads();
    const float rsum = (red[4] + red[5]) + (red[6] + red[7]);
    const float inv = 1.0f / rsum;

    const int wv = t >> 6;
    const int d = t & 63;
    float ctx = 0.f;
#pragma unroll 8
    for (int c = wv; c < SEQ; c += 4) {
      ctx = fmaf(sc[c], vg[((size_t)h * SEQ + c) * HD + d], ctx);
    }
    ctxp[wv][d] = ctx;
    __syncthreads();
    if (t < HD) {
      const float r = ((ctxp[0][t] + ctxp[1][t]) + (ctxp[2][t] + ctxp[3][t])) * inv;
      out[(size_t)i * DIM + h * HD + t] = r;
    }
  }
}

// ---------------- host ----------------
extern "C" void kernel_launch(void* const* d_in, const int* in_sizes, int n_in,
                              void* d_out, int out_size, void* d_ws, size_t ws_size,
                              hipStream_t stream) {
  const float* hs = (const float*)d_in[0];
  const int* mask = (const int*)d_in[13];

  float* q  = (float*)d_ws;                      // 6 x 4MB fp32 projections
  float* kx = q  + (size_t)SEQ * DIM;
  float* vx = kx + (size_t)SEQ * DIM;
  float* qg = vx + (size_t)SEQ * DIM;
  float* kg = qg + (size_t)SEQ * DIM;
  float* vg = kg + (size_t)SEQ * DIM;
  int* gcols = (int*)(vg + (size_t)SEQ * DIM);   // 16KB reserved
  unsigned short* Xcat = (unsigned short*)((char*)gcols + 16384);  // 6MB
  unsigned short* Wcat0 = Xcat + (size_t)SEQ * KCAT;               // 9MB
  unsigned short* qbb = Wcat0 + (size_t)6 * DIM * KCAT;            // 3 x 2MB bf16
  unsigned short* kbb = qbb + (size_t)SEQ * DIM;
  unsigned short* vbb = kbb + (size_t)SEQ * DIM;

  float* out  = (float*)d_out;            // [1,S,DIM]
  float* attn = out + (size_t)SEQ * DIM;  // [1,H,S,S] -- written densely, no memset

  hipLaunchKernelGGL(setup_kernel, dim3(1), dim3(256), 0, stream, mask, gcols);
  hipLaunchKernelGGL(convert_x_kernel, dim3(SEQ * DIM / 1024), dim3(256), 0, stream,
                     hs, Xcat);

  WArgs wa;
  PMArgs pm;
  float* pouts[6] = {q, kx, vx, qg, kg, vg};
  unsigned short* poutb[6] = {qbb, kbb, vbb, nullptr, nullptr, nullptr};
  for (int p = 0; p < 6; ++p) {
    wa.W[p] = (const float*)d_in[1 + 2 * p];
    wa.Wc[p] = Wcat0 + (size_t)p * DIM * KCAT;
    pm.Wc[p] = wa.Wc[p];
    pm.b[p] = (const float*)d_in[2 + 2 * p];
    pm.out[p] = pouts[p];
    pm.outb[p] = poutb[p];
  }
  hipLaunchKernelGGL(convert_w_kernel, dim3(DIM * DIM / 1024, 6), dim3(256), 0,
                     stream, wa);

  dim3 g1(SEQ / 128, DIM / 64, 6);
  hipLaunchKernelGGL(proj_mfma_kernel, g1, dim3(256), 0, stream, Xcat, pm);

  dim3 g2(SEQ / QR, HEADS);
  hipLaunchKernelGGL(local_attn_tile_kernel, g2, dim3(256), 0, stream, qbb, kbb,
                     vbb, mask, gcols, out, attn);
  hipLaunchKernelGGL(growrow_attn_kernel, dim3(256), dim3(256), 0, stream, q, kx,
                     mask, gcols, attn);
  hipLaunchKernelGGL(global_attn_kernel, dim3(256), dim3(256), 0, stream, qg, kg,
                     vg, mask, gcols, out);
}

// Round 7
// 159.861 us; speedup vs baseline: 13.4240x; 1.0251x over previous
//
#include <hip/hip_runtime.h>

#define SEQ 2048
#define DIM 512
#define HEADS 8
#define HD 64
#define WIN 128
#define NSMAX 320  // 273 band-union + up to 32 global cols + pad
#define KCAT 1536  // 3x bf16-split K
#define QR 16      // query rows per local-attn block

typedef short bf16x8 __attribute__((ext_vector_type(8)));
typedef float f32x4 __attribute__((ext_vector_type(4)));

__device__ inline unsigned short f2bf(float x) {
  unsigned u = __float_as_uint(x);
  unsigned r = (u + 0x7FFF + ((u >> 16) & 1)) >> 16;  // RTNE
  return (unsigned short)r;
}
__device__ inline float bf2f(unsigned short s) {
  return __uint_as_float((unsigned)s << 16);
}

// ---------------- convert X -> Xcat = [hi | hi | lo] (2048 x 1536 bf16) -------
__global__ __launch_bounds__(256) void convert_x_kernel(
    const float* __restrict__ X, unsigned short* __restrict__ Xc) {
  const int idx = (blockIdx.x * 256 + threadIdx.x) * 4;
  const int m = idx >> 9, k = idx & 511;
  const float4 xv = *(const float4*)&X[idx];
  ushort4 hi, lo;
  hi.x = f2bf(xv.x); lo.x = f2bf(xv.x - bf2f(hi.x));
  hi.y = f2bf(xv.y); lo.y = f2bf(xv.y - bf2f(hi.y));
  hi.z = f2bf(xv.z); lo.z = f2bf(xv.z - bf2f(hi.z));
  hi.w = f2bf(xv.w); lo.w = f2bf(xv.w - bf2f(hi.w));
  unsigned short* row = Xc + (size_t)m * KCAT;
  *(ushort4*)&row[k] = hi;
  *(ushort4*)&row[k + 512] = hi;
  *(ushort4*)&row[k + 1024] = lo;
}

// ---------------- convert W_p -> Wcat_p = [hi | lo | hi] (512 x 1536 bf16) ----
struct WArgs { const float* W[6]; unsigned short* Wc[6]; };
__global__ __launch_bounds__(256) void convert_w_kernel(WArgs a) {
  const int p = blockIdx.y;
  const float* __restrict__ W = a.W[p];
  unsigned short* __restrict__ Wc = a.Wc[p];
  const int idx = (blockIdx.x * 256 + threadIdx.x) * 4;
  const int n = idx >> 9, k = idx & 511;
  const float4 xv = *(const float4*)&W[idx];
  ushort4 hi, lo;
  hi.x = f2bf(xv.x); lo.x = f2bf(xv.x - bf2f(hi.x));
  hi.y = f2bf(xv.y); lo.y = f2bf(xv.y - bf2f(hi.y));
  hi.z = f2bf(xv.z); lo.z = f2bf(xv.z - bf2f(hi.z));
  hi.w = f2bf(xv.w); lo.w = f2bf(xv.w - bf2f(hi.w));
  unsigned short* row = Wc + (size_t)n * KCAT;
  *(ushort4*)&row[k] = hi;
  *(ushort4*)&row[k + 512] = lo;
  *(ushort4*)&row[k + 1024] = hi;
}

// ---------------- MFMA projection GEMM, 2-phase dbuf + global_load_lds -------
// LDS layout: slot (row, c) holds global chunk c^(row&7)  (involution swizzle).
// global_load_lds: linear LDS dest (base + lane*16), per-lane pre-swizzled src.
struct PMArgs {
  const unsigned short* Wc[6];
  const float* b[6];
  float* out[6];             // fp32 outputs (null = skip)
  unsigned short* outb[6];   // bf16 copies (q,k,v only; else null)
};
__global__ __launch_bounds__(256) void proj_mfma_kernel(
    const unsigned short* __restrict__ Xc, PMArgs a) {
  const int p = blockIdx.z;
  const unsigned short* __restrict__ Wc = a.Wc[p];
  const float* __restrict__ bias = a.b[p];
  float* __restrict__ out = a.out[p];
  unsigned short* __restrict__ outb = a.outb[p];
  const float scale = (p == 0 || p == 3) ? 0.125f : 1.0f;

  __shared__ __align__(16) unsigned short As[2][128 * 64];  // 2 x 16KB
  __shared__ __align__(16) unsigned short Bs[2][64 * 64];   // 2 x 8KB

  const int t = threadIdx.x;
  const int w = t >> 6, l = t & 63;
  const int m0 = blockIdx.x * 128, n0 = blockIdx.y * 64;

  f32x4 acc[2][4];
#pragma unroll
  for (int i = 0; i < 2; ++i)
#pragma unroll
    for (int j = 0; j < 4; ++j) acc[i][j] = (f32x4)0.0f;

  auto stage = [&](int buf, int k0) {
    // A: 1024 slots of 16B; wave w covers [w*256, w*256+256) in 4 calls
#pragma unroll
    for (int i = 0; i < 4; ++i) {
      const int slot = w * 256 + i * 64 + l;
      const int row = slot >> 3, cs = slot & 7;
      const unsigned short* src =
          Xc + (size_t)(m0 + row) * KCAT + k0 + ((cs ^ (row & 7)) << 3);
      __builtin_amdgcn_global_load_lds(
          (const __attribute__((address_space(1))) void*)src,
          (__attribute__((address_space(3))) void*)&As[buf][(w * 256 + i * 64) * 8],
          16, 0, 0);
    }
    // B: 512 slots; wave w covers [w*128, w*128+128) in 2 calls
#pragma unroll
    for (int i = 0; i < 2; ++i) {
      const int slot = w * 128 + i * 64 + l;
      const int row = slot >> 3, cs = slot & 7;
      const unsigned short* src =
          Wc + (size_t)(n0 + row) * KCAT + k0 + ((cs ^ (row & 7)) << 3);
      __builtin_amdgcn_global_load_lds(
          (const __attribute__((address_space(1))) void*)src,
          (__attribute__((address_space(3))) void*)&Bs[buf][(w * 128 + i * 64) * 8],
          16, 0, 0);
    }
  };

  stage(0, 0);
  __syncthreads();  // implicit vmcnt(0): buf0 ready
  int cur = 0;
  for (int kt = 0; kt < KCAT / 64; ++kt) {
    if (kt < KCAT / 64 - 1) stage(cur ^ 1, (kt + 1) * 64);  // prefetch in flight
    const unsigned short* __restrict__ Ab = As[cur];
    const unsigned short* __restrict__ Bb = Bs[cur];
#pragma unroll
    for (int s = 0; s < 2; ++s) {
      const int kc = s * 4 + (l >> 4);
      bf16x8 af[2], bfr[4];
#pragma unroll
      for (int fm = 0; fm < 2; ++fm) {
        const int row = w * 32 + fm * 16 + (l & 15);
        af[fm] = *(const bf16x8*)&Ab[row * 64 + ((kc ^ (row & 7)) << 3)];
      }
#pragma unroll
      for (int fn = 0; fn < 4; ++fn) {
        const int row = fn * 16 + (l & 15);
        bfr[fn] = *(const bf16x8*)&Bb[row * 64 + ((kc ^ (row & 7)) << 3)];
      }
#pragma unroll
      for (int fm = 0; fm < 2; ++fm)
#pragma unroll
        for (int fn = 0; fn < 4; ++fn)
          acc[fm][fn] = __builtin_amdgcn_mfma_f32_16x16x32_bf16(
              af[fm], bfr[fn], acc[fm][fn], 0, 0, 0);
    }
    __syncthreads();  // drains prefetch (vmcnt 0) + protects cur buf reads
    cur ^= 1;
  }

  const int h = n0 >> 6;
  const int col = l & 15, rb = (l >> 4) * 4;
#pragma unroll
  for (int fn = 0; fn < 4; ++fn) {
    const float bv = bias[n0 + fn * 16 + col];
#pragma unroll
    for (int fm = 0; fm < 2; ++fm) {
#pragma unroll
      for (int r = 0; r < 4; ++r) {
        const int m = m0 + w * 32 + fm * 16 + rb + r;
        const size_t oi = ((size_t)h * SEQ + m) * HD + fn * 16 + col;
        const float val = (acc[fm][fn][r] + bv) * scale;
        if (out) out[oi] = val;
        if (outb) outb[oi] = f2bf(val);
      }
    }
  }
}

// ---------------- setup: ordered compact list of global columns ----------------
__global__ __launch_bounds__(256) void setup_kernel(const int* __restrict__ mask,
                                                    int* __restrict__ g) {
  __shared__ int wtot[4];
  const int t = threadIdx.x;
  const int lane = t & 63;
  const int wv = t >> 6;
  int loc[8];
  int n = 0;
  const int base = t * 8;
#pragma unroll
  for (int j = 0; j < 8; ++j) {
    const int c = base + j;
    if (mask[c] == -1) loc[n++] = c;
  }
  int x = n;
#pragma unroll
  for (int o = 1; o < 64; o <<= 1) {
    const int y = __shfl_up(x, o);
    if (lane >= o) x += y;
  }
  if (lane == 63) wtot[wv] = x;
  __syncthreads();
  int basew = 0;
  for (int w = 0; w < wv; ++w) basew += wtot[w];
  if (t == 255) g[0] = basew + x;
  const int off = basew + x - n;
  for (int j = 0; j < n; ++j) g[1 + off + j] = loc[j];
}

// ---------------- reduction helpers ----------------
__device__ inline float wave_max(float x) {
#pragma unroll
  for (int o = 32; o > 0; o >>= 1) x = fmaxf(x, __shfl_xor(x, o));
  return x;
}
__device__ inline float wave_sum(float x) {
#pragma unroll
  for (int o = 32; o > 0; o >>= 1) x += __shfl_xor(x, o);
  return x;
}

// ---------------- MFMA local attention: 16 rows/block, dense attn writes -----
__global__ __launch_bounds__(256) void local_attn_tile_kernel(
    const unsigned short* __restrict__ qb, const unsigned short* __restrict__ kb,
    const unsigned short* __restrict__ vb, const int* __restrict__ mask,
    const int* __restrict__ g, float* __restrict__ out,
    float* __restrict__ attn) {
  const int h = blockIdx.y;
  const int r0 = blockIdx.x * QR;
  const int t = threadIdx.x;
  const int w = t >> 6, l = t & 63;
  const int g4 = l >> 4;

  __shared__ __align__(16) unsigned short qs[QR * 64];     // swizzled Q, 2KB
  __shared__ __align__(16) unsigned short ks[64 * 64];     // K chunk / V^T chunk, 8KB
  __shared__ __align__(16) unsigned short pbf[QR * NSMAX]; // P bf16 swizzled, 10KB
  __shared__ int scol[NSMAX];
  __shared__ int scm[NSMAX];
  __shared__ int mrow[QR];
  __shared__ float pmax[4][QR], psum[4][QR];
  __shared__ float rmaxs[QR], rinvs[QR];

  const int nglob_raw = g[0];
  const int nglob = nglob_raw < 32 ? nglob_raw : 32;
  const int lo = (r0 - WIN) > 0 ? (r0 - WIN) : 0;
  const int hi = (r0 + QR - 1 + WIN) < (SEQ - 1) ? (r0 + QR - 1 + WIN) : (SEQ - 1);
  const int blen = hi - lo + 1;
  const int nslots = blen + nglob;

  if (t < QR) mrow[t] = mask[r0 + t];
  for (int j = t; j < NSMAX; j += 256) {
    int c = lo;
    if (j < blen) c = lo + j;
    else if (j < nslots) c = g[1 + j - blen];
    scol[j] = c;
    scm[j] = mask[c];
  }
  // Q stage: QR*8 = 128 16B chunks
  if (t < 128) {
    const int row = t >> 3, ch = t & 7;
    *(int4*)&qs[row * 64 + ((ch ^ (row & 7)) << 3)] =
        *(const int4*)&qb[((size_t)h * SEQ + r0 + row) * HD + ch * 8];
  }

  // ---- score phase: 5 chunks of 64 slots, MFMA 16x16x32 ----
  f32x4 acc[5];
#pragma unroll
  for (int c = 0; c < 5; ++c) acc[c] = (f32x4)0.0f;

#pragma unroll
  for (int c = 0; c < 5; ++c) {
    __syncthreads();
    const int j0 = c * 64;
#pragma unroll
    for (int l2 = 0; l2 < 2; ++l2) {
      const int idx = t + l2 * 256;
      const int sl = idx >> 3, ch = idx & 7;
      const int cc = scol[j0 + sl];
      *(int4*)&ks[sl * 64 + ((ch ^ (sl & 7)) << 3)] =
          *(const int4*)&kb[((size_t)h * SEQ + cc) * HD + ch * 8];
    }
    __syncthreads();
    const int rA = l & 15;
    const int slB = w * 16 + (l & 15);
#pragma unroll
    for (int s = 0; s < 2; ++s) {
      const int kc = s * 4 + g4;
      const bf16x8 af = *(const bf16x8*)&qs[rA * 64 + ((kc ^ (rA & 7)) << 3)];
      const bf16x8 bf = *(const bf16x8*)&ks[slB * 64 + ((kc ^ (slB & 7)) << 3)];
      acc[c] = __builtin_amdgcn_mfma_f32_16x16x32_bf16(af, bf, acc[c], 0, 0, 0);
    }
  }

  // ---- mask + row max ----
  float pmx[4] = {-3e30f, -3e30f, -3e30f, -3e30f};
#pragma unroll
  for (int c = 0; c < 5; ++c) {
    const int n = 64 * c + 16 * w + (l & 15);
    const int cc = scol[n], mc = scm[n];
    const bool gl = (n >= blen);
#pragma unroll
    for (int r = 0; r < 4; ++r) {
      const int m = r0 + g4 * 4 + r;
      bool ok;
      if (!gl) {
        const int dist = m > cc ? m - cc : cc - m;
        ok = (mc != 0) && (dist <= WIN || mc == -1);
      } else {
        ok = (n < nslots) && (cc < lo || cc > hi);
      }
      const float s = ok ? acc[c][r] : -1e30f;
      acc[c][r] = s;
      pmx[r] = fmaxf(pmx[r], s);
    }
  }
#pragma unroll
  for (int off = 1; off < 16; off <<= 1)
#pragma unroll
    for (int r = 0; r < 4; ++r) pmx[r] = fmaxf(pmx[r], __shfl_xor(pmx[r], off));
  if ((l & 15) == 0)
#pragma unroll
    for (int r = 0; r < 4; ++r) pmax[w][g4 * 4 + r] = pmx[r];
  __syncthreads();
  if (t < QR)
    rmaxs[t] = fmaxf(fmaxf(pmax[0][t], pmax[1][t]), fmaxf(pmax[2][t], pmax[3][t]));
  __syncthreads();

  // ---- exp + row sum + P->bf16 LDS ----
  float rmx[4], psm[4] = {0.f, 0.f, 0.f, 0.f};
#pragma unroll
  for (int r = 0; r < 4; ++r) rmx[r] = rmaxs[g4 * 4 + r];
#pragma unroll
  for (int c = 0; c < 5; ++c)
#pragma unroll
    for (int r = 0; r < 4; ++r) {
      const float s = acc[c][r];
      const float p = (s > -1e29f) ? __expf(s - rmx[r]) : 0.0f;
      acc[c][r] = p;
      psm[r] += p;
    }
#pragma unroll
  for (int off = 1; off < 16; off <<= 1)
#pragma unroll
    for (int r = 0; r < 4; ++r) psm[r] += __shfl_xor(psm[r], off);
  if ((l & 15) == 0)
#pragma unroll
    for (int r = 0; r < 4; ++r) psum[w][g4 * 4 + r] = psm[r];
#pragma unroll
  for (int c = 0; c < 5; ++c) {
    const int n = 64 * c + 16 * w + (l & 15);
#pragma unroll
    for (int r = 0; r < 4; ++r) {
      const int m = g4 * 4 + r;
      pbf[m * NSMAX + (((n >> 3) ^ (m & 7)) << 3) + (n & 7)] = f2bf(acc[c][r]);
    }
  }
  __syncthreads();
  if (t < QR) rinvs[t] = 1.0f / (psum[0][t] + psum[1][t] + psum[2][t] + psum[3][t]);
  __syncthreads();

  // ---- dense attn zero-fill (outside band; full row for non-normal rows) ----
  {
    const int row = t >> 4, l16 = t & 15;
    const int mi = mrow[row];
    float* __restrict__ arow =
        attn + (size_t)h * SEQ * SEQ + (size_t)(r0 + row) * SEQ;
    const float4 z4 = make_float4(0.f, 0.f, 0.f, 0.f);
    const int lof4 = lo >> 2, hif4 = (hi + 1) >> 2;
    for (int f = l16; f < lof4; f += 16) *(float4*)&arow[f * 4] = z4;
    for (int f = hif4 + l16; f < 512; f += 16) *(float4*)&arow[f * 4] = z4;
    if (mi != 1)
      for (int f = lof4 + l16; f < hif4; f += 16) *(float4*)&arow[f * 4] = z4;
  }
  __syncthreads();  // zeros land before p-stores (glob cols overlap zero region)

  // ---- p-stores from registers (normal rows only) ----
#pragma unroll
  for (int c = 0; c < 5; ++c) {
    const int n = 64 * c + 16 * w + (l & 15);
    const int cc = scol[n];
    const bool gl = (n >= blen);
    const bool gok = gl && (n < nslots) && (cc < lo || cc > hi);
#pragma unroll
    for (int r = 0; r < 4; ++r) {
      const int m = g4 * 4 + r;
      if (mrow[m] == 1 && (!gl || gok))
        attn[(size_t)h * SEQ * SEQ + (size_t)(r0 + m) * SEQ + cc] =
            acc[c][r] * rinvs[m];
    }
  }

  // ---- PV phase: 5 chunks; V^T staged transposed+swizzled into ks ----
  f32x4 cacc = (f32x4)0.0f;
#pragma unroll
  for (int c = 0; c < 5; ++c) {
    __syncthreads();
    const int j0 = c * 64;
    {
      const int sl = t & 63;
      const int cc = scol[j0 + sl];
#pragma unroll
      for (int l2 = 0; l2 < 4; ++l2) {
        const int d4 = (t >> 6) + l2 * 4;
        const ushort4 vv = *(const ushort4*)&vb[((size_t)h * SEQ + cc) * HD + d4 * 4];
#pragma unroll
        for (int e = 0; e < 4; ++e) {
          const int d = d4 * 4 + e;
          ks[d * 64 + (((sl >> 3) ^ (d & 7)) << 3) + (sl & 7)] =
              ((const unsigned short*)&vv)[e];
        }
      }
    }
    __syncthreads();
    const int rA = l & 15;
    const int dB = w * 16 + (l & 15);
#pragma unroll
    for (int s = 0; s < 2; ++s) {
      const int pc = c * 8 + s * 4 + g4;  // pbf slot-chunk
      const int kc = s * 4 + g4;          // vsT slot-chunk
      const bf16x8 af = *(const bf16x8*)&pbf[rA * NSMAX + ((pc ^ (rA & 7)) << 3)];
      const bf16x8 bf = *(const bf16x8*)&ks[dB * 64 + ((kc ^ (dB & 7)) << 3)];
      cacc = __builtin_amdgcn_mfma_f32_16x16x32_bf16(af, bf, cacc, 0, 0, 0);
    }
  }

  // ---- out epilogue ----
  {
    const int d = w * 16 + (l & 15);
#pragma unroll
    for (int r = 0; r < 4; ++r) {
      const int m = g4 * 4 + r;
      const int mi = mrow[m];
      const float val = (mi == 0) ? 0.f : cacc[r] * rinvs[m];
      out[(size_t)(r0 + m) * DIM + h * HD + d] = val;
    }
  }
}

// ------- local-attn probabilities for GLOBAL rows (compact grid, no ctx) -------
__global__ __launch_bounds__(256) void growrow_attn_kernel(
    const float* __restrict__ q, const float* __restrict__ k,
    const int* __restrict__ mask, const int* __restrict__ g,
    float* __restrict__ attn) {
  const int nglob = g[0];
  const int j0 = blockIdx.x >> 3;
  const int h = blockIdx.x & 7;
  const int t = threadIdx.x;

  __shared__ float sc[SEQ];
  __shared__ float qrow[HD];
  __shared__ float red[8];

  for (int jj = j0; jj < nglob; jj += 32) {
    const int i = g[1 + jj];
    __syncthreads();
    if (t < HD) qrow[t] = q[((size_t)h * SEQ + i) * HD + t];
    __syncthreads();

    float lmax = -1e30f;
#pragma unroll 2
    for (int c = t; c < SEQ; c += 256) {
      const bool ok = (mask[c] != 0);
      const float* kr = &k[((size_t)h * SEQ + c) * HD];
      float a0 = 0.f, a1 = 0.f, a2 = 0.f, a3 = 0.f;
#pragma unroll
      for (int d = 0; d < HD; d += 4) {
        const float4 kv = *(const float4*)&kr[d];
        const float4 qv = *(const float4*)&qrow[d];
        a0 = fmaf(qv.x, kv.x, a0);
        a1 = fmaf(qv.y, kv.y, a1);
        a2 = fmaf(qv.z, kv.z, a2);
        a3 = fmaf(qv.w, kv.w, a3);
      }
      const float s = ok ? ((a0 + a1) + (a2 + a3)) : -1e30f;
      lmax = fmaxf(lmax, s);
      sc[c] = s;
    }
    const float wm = wave_max(lmax);
    if ((t & 63) == 0) red[t >> 6] = wm;
    __syncthreads();
    const float rmax = fmaxf(fmaxf(red[0], red[1]), fmaxf(red[2], red[3]));

    float lsum = 0.f;
#pragma unroll 2
    for (int c = t; c < SEQ; c += 256) {
      const float s = sc[c];
      const float pp = (s > -1e29f) ? __expf(s - rmax) : 0.0f;
      sc[c] = pp;
      lsum += pp;
    }
    const float wsum = wave_sum(lsum);
    __syncthreads();
    if ((t & 63) == 0) red[4 + (t >> 6)] = wsum;
    __syncthreads();
    const float rsum = (red[4] + red[5]) + (red[6] + red[7]);
    const float inv = 1.0f / rsum;

    float* __restrict__ arow = attn + (size_t)h * SEQ * SEQ + (size_t)i * SEQ;
#pragma unroll 2
    for (int c = t; c < SEQ; c += 256) {
      const float pp = sc[c];
      if (pp != 0.0f) arow[c] = pp * inv;
    }
  }
}

// ---------------- Global attention branch (compact grid) ----------------
__global__ __launch_bounds__(256) void global_attn_kernel(
    const float* __restrict__ qg, const float* __restrict__ kg,
    const float* __restrict__ vg, const int* __restrict__ mask,
    const int* __restrict__ g, float* __restrict__ out) {
  const int nglob = g[0];
  const int j0 = blockIdx.x >> 3;
  const int h = blockIdx.x & 7;
  const int t = threadIdx.x;

  __shared__ float sc[SEQ];
  __shared__ float qrow[HD];
  __shared__ float red[8];
  __shared__ float ctxp[4][HD];

  for (int jj = j0; jj < nglob; jj += 32) {
    const int i = g[1 + jj];
    __syncthreads();
    if (t < HD) qrow[t] = qg[((size_t)h * SEQ + i) * HD + t];
    __syncthreads();

    float lmax = -1e30f;
#pragma unroll 2
    for (int c = t; c < SEQ; c += 256) {
      const bool ok = (mask[c] != 0);
      const float* kr = &kg[((size_t)h * SEQ + c) * HD];
      float a0 = 0.f, a1 = 0.f, a2 = 0.f, a3 = 0.f;
#pragma unroll
      for (int d = 0; d < HD; d += 4) {
        const float4 kv = *(const float4*)&kr[d];
        const float4 qv = *(const float4*)&qrow[d];
        a0 = fmaf(qv.x, kv.x, a0);
        a1 = fmaf(qv.y, kv.y, a1);
        a2 = fmaf(qv.z, kv.z, a2);
        a3 = fmaf(qv.w, kv.w, a3);
      }
      const float s = ok ? ((a0 + a1) + (a2 + a3)) : -1e30f;
      lmax = fmaxf(lmax, s);
      sc[c] = s;
    }
    const float wm = wave_max(lmax);
    if ((t & 63) == 0) red[t >> 6] = wm;
    __syncthreads();
    const float rmax = fmaxf(fmaxf(red[0], red[1]), fmaxf(red[2], red[3]));

    float lsum = 0.f;
#pragma unroll 2
    for (int c = t; c < SEQ; c += 256) {
      const float s = sc[c];
      const float pp = (s > -1e29f) ? __expf(s - rmax) : 0.0f;
      sc[c] = pp;
      lsum += pp;
    }
    const float wsum = wave_sum(lsum);
    __syncthreads();
    if ((t & 63) == 0) red[4 + (t >> 6)] = wsum;
    __syncthreads();
    const float rsum = (red[4] + red[5]) + (red[6] + red[7]);
    const float inv = 1.0f / rsum;

    const int wv = t >> 6;
    const int d = t & 63;
    float ctx = 0.f;
#pragma unroll 8
    for (int c = wv; c < SEQ; c += 4) {
      ctx = fmaf(sc[c], vg[((size_t)h * SEQ + c) * HD + d], ctx);
    }
    ctxp[wv][d] = ctx;
    __syncthreads();
    if (t < HD) {
      const float r = ((ctxp[0][t] + ctxp[1][t]) + (ctxp[2][t] + ctxp[3][t])) * inv;
      out[(size_t)i * DIM + h * HD + t] = r;
    }
  }
}

// ---------------- host ----------------
extern "C" void kernel_launch(void* const* d_in, const int* in_sizes, int n_in,
                              void* d_out, int out_size, void* d_ws, size_t ws_size,
                              hipStream_t stream) {
  const float* hs = (const float*)d_in[0];
  const int* mask = (const int*)d_in[13];

  float* q  = (float*)d_ws;                      // 6 x 4MB fp32 projections
  float* kx = q  + (size_t)SEQ * DIM;
  float* vx = kx + (size_t)SEQ * DIM;            // (vx fp32 unused; slot kept)
  float* qg = vx + (size_t)SEQ * DIM;
  float* kg = qg + (size_t)SEQ * DIM;
  float* vg = kg + (size_t)SEQ * DIM;
  int* gcols = (int*)(vg + (size_t)SEQ * DIM);   // 16KB reserved
  unsigned short* Xcat = (unsigned short*)((char*)gcols + 16384);  // 6MB
  unsigned short* Wcat0 = Xcat + (size_t)SEQ * KCAT;               // 9MB
  unsigned short* qbb = Wcat0 + (size_t)6 * DIM * KCAT;            // 3 x 2MB bf16
  unsigned short* kbb = qbb + (size_t)SEQ * DIM;
  unsigned short* vbb = kbb + (size_t)SEQ * DIM;

  float* out  = (float*)d_out;            // [1,S,DIM]
  float* attn = out + (size_t)SEQ * DIM;  // [1,H,S,S] -- written densely, no memset

  hipLaunchKernelGGL(setup_kernel, dim3(1), dim3(256), 0, stream, mask, gcols);
  hipLaunchKernelGGL(convert_x_kernel, dim3(SEQ * DIM / 1024), dim3(256), 0, stream,
                     hs, Xcat);

  WArgs wa;
  PMArgs pm;
  float* pouts[6] = {q, kx, nullptr, qg, kg, vg};  // vx fp32 dead -> skip
  unsigned short* poutb[6] = {qbb, kbb, vbb, nullptr, nullptr, nullptr};
  for (int p = 0; p < 6; ++p) {
    wa.W[p] = (const float*)d_in[1 + 2 * p];
    wa.Wc[p] = Wcat0 + (size_t)p * DIM * KCAT;
    pm.Wc[p] = wa.Wc[p];
    pm.b[p] = (const float*)d_in[2 + 2 * p];
    pm.out[p] = pouts[p];
    pm.outb[p] = poutb[p];
  }
  hipLaunchKernelGGL(convert_w_kernel, dim3(DIM * DIM / 1024, 6), dim3(256), 0,
                     stream, wa);

  dim3 g1(SEQ / 128, DIM / 64, 6);
  hipLaunchKernelGGL(proj_mfma_kernel, g1, dim3(256), 0, stream, Xcat, pm);

  dim3 g2(SEQ / QR, HEADS);
  hipLaunchKernelGGL(local_attn_tile_kernel, g2, dim3(256), 0, stream, qbb, kbb,
                     vbb, mask, gcols, out, attn);
  hipLaunchKernelGGL(growrow_attn_kernel, dim3(256), dim3(256), 0, stream, q, kx,
                     mask, gcols, attn);
  hipLaunchKernelGGL(global_attn_kernel, dim3(256), dim3(256), 0, stream, qg, kg,
                     vg, mask, gcols, out);
}

// Round 8
// 123.637 us; speedup vs baseline: 17.3571x; 1.2930x over previous
//
#include <hip/hip_runtime.h>

#define SEQ 2048
#define DIM 512
#define HEADS 8
#define HD 64
#define WIN 128
#define NSMAX 320  // 273 band-union + up to 32 global cols + pad
#define KCAT 1536  // 3x bf16-split K
#define QR 16      // query rows per local-attn block

typedef short bf16x8 __attribute__((ext_vector_type(8)));
typedef float f32x4 __attribute__((ext_vector_type(4)));

__device__ inline unsigned short f2bf(float x) {
  unsigned u = __float_as_uint(x);
  unsigned r = (u + 0x7FFF + ((u >> 16) & 1)) >> 16;  // RTNE
  return (unsigned short)r;
}
__device__ inline float bf2f(unsigned short s) {
  return __uint_as_float((unsigned)s << 16);
}

struct WArgs { const float* W[6]; unsigned short* Wc[6]; };

// ---------------- fused prep: convert_x | convert_w | setup ----------------
__global__ __launch_bounds__(256) void prep_kernel(
    const float* __restrict__ X, unsigned short* __restrict__ Xc, WArgs a,
    const int* __restrict__ mask, int* __restrict__ g) {
  const int bid = blockIdx.x;
  const int t = threadIdx.x;

  if (bid < 1024) {  // convert X -> Xcat = [hi | hi | lo]
    const int idx = (bid * 256 + t) * 4;
    const int m = idx >> 9, k = idx & 511;
    const float4 xv = *(const float4*)&X[idx];
    ushort4 hi, lo;
    hi.x = f2bf(xv.x); lo.x = f2bf(xv.x - bf2f(hi.x));
    hi.y = f2bf(xv.y); lo.y = f2bf(xv.y - bf2f(hi.y));
    hi.z = f2bf(xv.z); lo.z = f2bf(xv.z - bf2f(hi.z));
    hi.w = f2bf(xv.w); lo.w = f2bf(xv.w - bf2f(hi.w));
    unsigned short* row = Xc + (size_t)m * KCAT;
    *(ushort4*)&row[k] = hi;
    *(ushort4*)&row[k + 512] = hi;
    *(ushort4*)&row[k + 1024] = lo;
    return;
  }
  if (bid < 2560) {  // convert W_p -> Wcat_p = [hi | lo | hi]
    const int b = bid - 1024;
    const int p = b >> 8;
    const float* __restrict__ W = a.W[p];
    unsigned short* __restrict__ Wc = a.Wc[p];
    const int idx = ((b & 255) * 256 + t) * 4;
    const float4 xv = *(const float4*)&W[idx];
    ushort4 hi, lo;
    hi.x = f2bf(xv.x); lo.x = f2bf(xv.x - bf2f(hi.x));
    hi.y = f2bf(xv.y); lo.y = f2bf(xv.y - bf2f(hi.y));
    hi.z = f2bf(xv.z); lo.z = f2bf(xv.z - bf2f(hi.z));
    hi.w = f2bf(xv.w); lo.w = f2bf(xv.w - bf2f(hi.w));
    unsigned short* row = Wc + (size_t)(idx >> 9) * KCAT;
    const int k = idx & 511;
    *(ushort4*)&row[k] = hi;
    *(ushort4*)&row[k + 512] = lo;
    *(ushort4*)&row[k + 1024] = hi;
    return;
  }
  // setup: ordered compact list of global columns
  {
    __shared__ int wtot[4];
    const int lane = t & 63;
    const int wv = t >> 6;
    int loc[8];
    int n = 0;
    const int base = t * 8;
#pragma unroll
    for (int j = 0; j < 8; ++j) {
      const int c = base + j;
      if (mask[c] == -1) loc[n++] = c;
    }
    int x = n;
#pragma unroll
    for (int o = 1; o < 64; o <<= 1) {
      const int y = __shfl_up(x, o);
      if (lane >= o) x += y;
    }
    if (lane == 63) wtot[wv] = x;
    __syncthreads();
    int basew = 0;
    for (int w = 0; w < wv; ++w) basew += wtot[w];
    if (t == 255) g[0] = basew + x;
    const int off = basew + x - n;
    for (int j = 0; j < n; ++j) g[1 + off + j] = loc[j];
  }
}

// ---------------- MFMA projection GEMM, 2-phase dbuf + global_load_lds -------
struct PMArgs {
  const unsigned short* Wc[6];
  const float* b[6];
  float* out[6];             // fp32 outputs (null = skip)
  unsigned short* outb[6];   // bf16 copies (q,k,v only; else null)
};
__global__ __launch_bounds__(256) void proj_mfma_kernel(
    const unsigned short* __restrict__ Xc, PMArgs a) {
  const int p = blockIdx.z;
  const unsigned short* __restrict__ Wc = a.Wc[p];
  const float* __restrict__ bias = a.b[p];
  float* __restrict__ out = a.out[p];
  unsigned short* __restrict__ outb = a.outb[p];
  const float scale = (p == 0 || p == 3) ? 0.125f : 1.0f;

  __shared__ __align__(16) unsigned short As[2][128 * 64];  // 2 x 16KB
  __shared__ __align__(16) unsigned short Bs[2][64 * 64];   // 2 x 8KB

  const int t = threadIdx.x;
  const int w = t >> 6, l = t & 63;
  const int m0 = blockIdx.x * 128, n0 = blockIdx.y * 64;

  f32x4 acc[2][4];
#pragma unroll
  for (int i = 0; i < 2; ++i)
#pragma unroll
    for (int j = 0; j < 4; ++j) acc[i][j] = (f32x4)0.0f;

  auto stage = [&](int buf, int k0) {
#pragma unroll
    for (int i = 0; i < 4; ++i) {
      const int slot = w * 256 + i * 64 + l;
      const int row = slot >> 3, cs = slot & 7;
      const unsigned short* src =
          Xc + (size_t)(m0 + row) * KCAT + k0 + ((cs ^ (row & 7)) << 3);
      __builtin_amdgcn_global_load_lds(
          (const __attribute__((address_space(1))) void*)src,
          (__attribute__((address_space(3))) void*)&As[buf][(w * 256 + i * 64) * 8],
          16, 0, 0);
    }
#pragma unroll
    for (int i = 0; i < 2; ++i) {
      const int slot = w * 128 + i * 64 + l;
      const int row = slot >> 3, cs = slot & 7;
      const unsigned short* src =
          Wc + (size_t)(n0 + row) * KCAT + k0 + ((cs ^ (row & 7)) << 3);
      __builtin_amdgcn_global_load_lds(
          (const __attribute__((address_space(1))) void*)src,
          (__attribute__((address_space(3))) void*)&Bs[buf][(w * 128 + i * 64) * 8],
          16, 0, 0);
    }
  };

  stage(0, 0);
  __syncthreads();
  int cur = 0;
  for (int kt = 0; kt < KCAT / 64; ++kt) {
    if (kt < KCAT / 64 - 1) stage(cur ^ 1, (kt + 1) * 64);
    const unsigned short* __restrict__ Ab = As[cur];
    const unsigned short* __restrict__ Bb = Bs[cur];
#pragma unroll
    for (int s = 0; s < 2; ++s) {
      const int kc = s * 4 + (l >> 4);
      bf16x8 af[2], bfr[4];
#pragma unroll
      for (int fm = 0; fm < 2; ++fm) {
        const int row = w * 32 + fm * 16 + (l & 15);
        af[fm] = *(const bf16x8*)&Ab[row * 64 + ((kc ^ (row & 7)) << 3)];
      }
#pragma unroll
      for (int fn = 0; fn < 4; ++fn) {
        const int row = fn * 16 + (l & 15);
        bfr[fn] = *(const bf16x8*)&Bb[row * 64 + ((kc ^ (row & 7)) << 3)];
      }
#pragma unroll
      for (int fm = 0; fm < 2; ++fm)
#pragma unroll
        for (int fn = 0; fn < 4; ++fn)
          acc[fm][fn] = __builtin_amdgcn_mfma_f32_16x16x32_bf16(
              af[fm], bfr[fn], acc[fm][fn], 0, 0, 0);
    }
    __syncthreads();
    cur ^= 1;
  }

  const int h = n0 >> 6;
  const int col = l & 15, rb = (l >> 4) * 4;
#pragma unroll
  for (int fn = 0; fn < 4; ++fn) {
    const float bv = bias[n0 + fn * 16 + col];
#pragma unroll
    for (int fm = 0; fm < 2; ++fm) {
#pragma unroll
      for (int r = 0; r < 4; ++r) {
        const int m = m0 + w * 32 + fm * 16 + rb + r;
        const size_t oi = ((size_t)h * SEQ + m) * HD + fn * 16 + col;
        const float val = (acc[fm][fn][r] + bv) * scale;
        if (out) out[oi] = val;
        if (outb) outb[oi] = f2bf(val);
      }
    }
  }
}

// ---------------- shared-mem layouts for fused attention ----------------
struct LocalSmem {
  unsigned short qs[QR * 64];      // 2KB  swizzled Q
  unsigned short ks[64 * 64];      // 8KB  K chunk / V^T chunk
  unsigned short pbf[QR * NSMAX];  // 10KB P bf16 swizzled
  int scol[NSMAX];
  int scm[NSMAX];
  int mrow[QR];
  float pmax[4][QR], psum[4][QR];
  float rmaxs[QR], rinvs[QR];
};
struct GlobSmem {
  float sc[SEQ];
  float qrow[HD];
  float red[8];
  float ctxp[4][HD];
};

__device__ inline float wave_max(float x) {
#pragma unroll
  for (int o = 32; o > 0; o >>= 1) x = fmaxf(x, __shfl_xor(x, o));
  return x;
}
__device__ inline float wave_sum(float x) {
#pragma unroll
  for (int o = 32; o > 0; o >>= 1) x += __shfl_xor(x, o);
  return x;
}

// ---------------- fused attention: local(1024) | growrow(256) | global(256) --
__global__ __launch_bounds__(256) void attn_fused_kernel(
    const unsigned short* __restrict__ qb, const unsigned short* __restrict__ kb,
    const unsigned short* __restrict__ vb, const float* __restrict__ q,
    const float* __restrict__ kx, const float* __restrict__ qg,
    const float* __restrict__ kg, const float* __restrict__ vg,
    const int* __restrict__ mask, const int* __restrict__ g,
    float* __restrict__ out, float* __restrict__ attn) {
  __shared__ __align__(16) unsigned char smem_raw[
      sizeof(LocalSmem) > sizeof(GlobSmem) ? sizeof(LocalSmem) : sizeof(GlobSmem)];
  const int bid = blockIdx.x;
  const int t = threadIdx.x;

  if (bid < 1024) {
    // ================= LOCAL: 16 query rows, owns attn+out for mi in {0,1} ===
    LocalSmem& S = *reinterpret_cast<LocalSmem*>(smem_raw);
    const int h = bid >> 7;
    const int r0 = (bid & 127) * QR;
    const int w = t >> 6, l = t & 63;
    const int g4 = l >> 4;

    const int nglob_raw = g[0];
    const int nglob = nglob_raw < 32 ? nglob_raw : 32;
    const int lo = (r0 - WIN) > 0 ? (r0 - WIN) : 0;
    const int hi = (r0 + QR - 1 + WIN) < (SEQ - 1) ? (r0 + QR - 1 + WIN) : (SEQ - 1);
    const int blen = hi - lo + 1;
    const int nslots = blen + nglob;

    if (t < QR) S.mrow[t] = mask[r0 + t];
    for (int j = t; j < NSMAX; j += 256) {
      int c = lo;
      if (j < blen) c = lo + j;
      else if (j < nslots) c = g[1 + j - blen];
      S.scol[j] = c;
      S.scm[j] = mask[c];
    }
    if (t < 128) {
      const int row = t >> 3, ch = t & 7;
      *(int4*)&S.qs[row * 64 + ((ch ^ (row & 7)) << 3)] =
          *(const int4*)&qb[((size_t)h * SEQ + r0 + row) * HD + ch * 8];
    }

    // ---- score phase ----
    f32x4 acc[5];
#pragma unroll
    for (int c = 0; c < 5; ++c) acc[c] = (f32x4)0.0f;

#pragma unroll
    for (int c = 0; c < 5; ++c) {
      __syncthreads();
      const int j0 = c * 64;
#pragma unroll
      for (int l2 = 0; l2 < 2; ++l2) {
        const int idx = t + l2 * 256;
        const int sl = idx >> 3, ch = idx & 7;
        const int cc = S.scol[j0 + sl];
        *(int4*)&S.ks[sl * 64 + ((ch ^ (sl & 7)) << 3)] =
            *(const int4*)&kb[((size_t)h * SEQ + cc) * HD + ch * 8];
      }
      __syncthreads();
      const int rA = l & 15;
      const int slB = w * 16 + (l & 15);
#pragma unroll
      for (int s = 0; s < 2; ++s) {
        const int kc = s * 4 + g4;
        const bf16x8 af = *(const bf16x8*)&S.qs[rA * 64 + ((kc ^ (rA & 7)) << 3)];
        const bf16x8 bf = *(const bf16x8*)&S.ks[slB * 64 + ((kc ^ (slB & 7)) << 3)];
        acc[c] = __builtin_amdgcn_mfma_f32_16x16x32_bf16(af, bf, acc[c], 0, 0, 0);
      }
    }

    // ---- mask + row max ----
    float pmx[4] = {-3e30f, -3e30f, -3e30f, -3e30f};
#pragma unroll
    for (int c = 0; c < 5; ++c) {
      const int n = 64 * c + 16 * w + (l & 15);
      const int cc = S.scol[n], mc = S.scm[n];
      const bool gl = (n >= blen);
#pragma unroll
      for (int r = 0; r < 4; ++r) {
        const int m = r0 + g4 * 4 + r;
        bool ok;
        if (!gl) {
          const int dist = m > cc ? m - cc : cc - m;
          ok = (mc != 0) && (dist <= WIN || mc == -1);
        } else {
          ok = (n < nslots) && (cc < lo || cc > hi);
        }
        const float s = ok ? acc[c][r] : -1e30f;
        acc[c][r] = s;
        pmx[r] = fmaxf(pmx[r], s);
      }
    }
#pragma unroll
    for (int off = 1; off < 16; off <<= 1)
#pragma unroll
      for (int r = 0; r < 4; ++r) pmx[r] = fmaxf(pmx[r], __shfl_xor(pmx[r], off));
    if ((l & 15) == 0)
#pragma unroll
      for (int r = 0; r < 4; ++r) S.pmax[w][g4 * 4 + r] = pmx[r];
    __syncthreads();
    if (t < QR)
      S.rmaxs[t] = fmaxf(fmaxf(S.pmax[0][t], S.pmax[1][t]),
                         fmaxf(S.pmax[2][t], S.pmax[3][t]));
    __syncthreads();

    // ---- exp + row sum + P->bf16 LDS ----
    float rmx[4], psm[4] = {0.f, 0.f, 0.f, 0.f};
#pragma unroll
    for (int r = 0; r < 4; ++r) rmx[r] = S.rmaxs[g4 * 4 + r];
#pragma unroll
    for (int c = 0; c < 5; ++c)
#pragma unroll
      for (int r = 0; r < 4; ++r) {
        const float s = acc[c][r];
        const float p = (s > -1e29f) ? __expf(s - rmx[r]) : 0.0f;
        acc[c][r] = p;
        psm[r] += p;
      }
#pragma unroll
    for (int off = 1; off < 16; off <<= 1)
#pragma unroll
      for (int r = 0; r < 4; ++r) psm[r] += __shfl_xor(psm[r], off);
    if ((l & 15) == 0)
#pragma unroll
      for (int r = 0; r < 4; ++r) S.psum[w][g4 * 4 + r] = psm[r];
#pragma unroll
    for (int c = 0; c < 5; ++c) {
      const int n = 64 * c + 16 * w + (l & 15);
#pragma unroll
      for (int r = 0; r < 4; ++r) {
        const int m = g4 * 4 + r;
        S.pbf[m * NSMAX + (((n >> 3) ^ (m & 7)) << 3) + (n & 7)] = f2bf(acc[c][r]);
      }
    }
    __syncthreads();
    if (t < QR)
      S.rinvs[t] = 1.0f / (S.psum[0][t] + S.psum[1][t] + S.psum[2][t] + S.psum[3][t]);
    __syncthreads();

    // ---- dense attn zero-fill: mi==1 outside band, mi==0 whole row, mi==-1 none
    {
      const int row = t >> 4, l16 = t & 15;
      const int mi = S.mrow[row];
      float* __restrict__ arow =
          attn + (size_t)h * SEQ * SEQ + (size_t)(r0 + row) * SEQ;
      const float4 z4 = make_float4(0.f, 0.f, 0.f, 0.f);
      const int lof4 = lo >> 2, hif4 = (hi + 1) >> 2;
      if (mi != -1) {
        for (int f = l16; f < lof4; f += 16) *(float4*)&arow[f * 4] = z4;
        for (int f = hif4 + l16; f < 512; f += 16) *(float4*)&arow[f * 4] = z4;
        if (mi == 0)
          for (int f = lof4 + l16; f < hif4; f += 16) *(float4*)&arow[f * 4] = z4;
      }
    }
    __syncthreads();  // zeros land before p-stores (glob cols overlap zero region)

    // ---- p-stores (normal rows only) ----
#pragma unroll
    for (int c = 0; c < 5; ++c) {
      const int n = 64 * c + 16 * w + (l & 15);
      const int cc = S.scol[n];
      const bool gl = (n >= blen);
      const bool gok = gl && (n < nslots) && (cc < lo || cc > hi);
#pragma unroll
      for (int r = 0; r < 4; ++r) {
        const int m = g4 * 4 + r;
        if (S.mrow[m] == 1 && (!gl || gok))
          attn[(size_t)h * SEQ * SEQ + (size_t)(r0 + m) * SEQ + cc] =
              acc[c][r] * S.rinvs[m];
      }
    }

    // ---- PV phase ----
    f32x4 cacc = (f32x4)0.0f;
#pragma unroll
    for (int c = 0; c < 5; ++c) {
      __syncthreads();
      const int j0 = c * 64;
      {
        const int sl = t & 63;
        const int cc = S.scol[j0 + sl];
#pragma unroll
        for (int l2 = 0; l2 < 4; ++l2) {
          const int d4 = (t >> 6) + l2 * 4;
          const ushort4 vv =
              *(const ushort4*)&vb[((size_t)h * SEQ + cc) * HD + d4 * 4];
#pragma unroll
          for (int e = 0; e < 4; ++e) {
            const int d = d4 * 4 + e;
            S.ks[d * 64 + (((sl >> 3) ^ (d & 7)) << 3) + (sl & 7)] =
                ((const unsigned short*)&vv)[e];
          }
        }
      }
      __syncthreads();
      const int rA = l & 15;
      const int dB = w * 16 + (l & 15);
#pragma unroll
      for (int s = 0; s < 2; ++s) {
        const int pc = c * 8 + s * 4 + g4;
        const int kc = s * 4 + g4;
        const bf16x8 af = *(const bf16x8*)&S.pbf[rA * NSMAX + ((pc ^ (rA & 7)) << 3)];
        const bf16x8 bf = *(const bf16x8*)&S.ks[dB * 64 + ((kc ^ (dB & 7)) << 3)];
        cacc = __builtin_amdgcn_mfma_f32_16x16x32_bf16(af, bf, cacc, 0, 0, 0);
      }
    }

    // ---- out epilogue (skip mi==-1: global path owns those rows) ----
    {
      const int d = w * 16 + (l & 15);
#pragma unroll
      for (int r = 0; r < 4; ++r) {
        const int m = g4 * 4 + r;
        const int mi = S.mrow[m];
        if (mi != -1) {
          const float val = (mi == 0) ? 0.f : cacc[r] * S.rinvs[m];
          out[(size_t)(r0 + m) * DIM + h * HD + d] = val;
        }
      }
    }
    return;
  }

  GlobSmem& S = *reinterpret_cast<GlobSmem*>(smem_raw);
  const int nglob = g[0];

  if (bid < 1280) {
    // ============ GROWROW: local-attn probs for mi==-1 rows (whole row) ======
    const int b = bid - 1024;
    const int j0 = b >> 3;
    const int h = b & 7;

    for (int jj = j0; jj < nglob; jj += 32) {
      const int i = g[1 + jj];
      __syncthreads();
      if (t < HD) S.qrow[t] = q[((size_t)h * SEQ + i) * HD + t];
      __syncthreads();

      float lmax = -1e30f;
#pragma unroll 2
      for (int c = t; c < SEQ; c += 256) {
        const bool ok = (mask[c] != 0);
        const float* kr = &kx[((size_t)h * SEQ + c) * HD];
        float a0 = 0.f, a1 = 0.f, a2 = 0.f, a3 = 0.f;
#pragma unroll
        for (int d = 0; d < HD; d += 4) {
          const float4 kv = *(const float4*)&kr[d];
          const float4 qv = *(const float4*)&S.qrow[d];
          a0 = fmaf(qv.x, kv.x, a0);
          a1 = fmaf(qv.y, kv.y, a1);
          a2 = fmaf(qv.z, kv.z, a2);
          a3 = fmaf(qv.w, kv.w, a3);
        }
        const float s = ok ? ((a0 + a1) + (a2 + a3)) : -1e30f;
        lmax = fmaxf(lmax, s);
        S.sc[c] = s;
      }
      const float wm = wave_max(lmax);
      if ((t & 63) == 0) S.red[t >> 6] = wm;
      __syncthreads();
      const float rmax = fmaxf(fmaxf(S.red[0], S.red[1]), fmaxf(S.red[2], S.red[3]));

      float lsum = 0.f;
#pragma unroll 2
      for (int c = t; c < SEQ; c += 256) {
        const float s = S.sc[c];
        const float pp = (s > -1e29f) ? __expf(s - rmax) : 0.0f;
        S.sc[c] = pp;
        lsum += pp;
      }
      const float wsum = wave_sum(lsum);
      __syncthreads();
      if ((t & 63) == 0) S.red[4 + (t >> 6)] = wsum;
      __syncthreads();
      const float rsum = (S.red[4] + S.red[5]) + (S.red[6] + S.red[7]);
      const float inv = 1.0f / rsum;

      float* __restrict__ arow = attn + (size_t)h * SEQ * SEQ + (size_t)i * SEQ;
#pragma unroll 2
      for (int c = t; c < SEQ; c += 256) arow[c] = S.sc[c] * inv;  // 0 for pad cols
    }
    return;
  }

  // ============ GLOBAL branch: out rows for mi==-1 ============
  {
    const int b = bid - 1280;
    const int j0 = b >> 3;
    const int h = b & 7;

    for (int jj = j0; jj < nglob; jj += 32) {
      const int i = g[1 + jj];
      __syncthreads();
      if (t < HD) S.qrow[t] = qg[((size_t)h * SEQ + i) * HD + t];
      __syncthreads();

      float lmax = -1e30f;
#pragma unroll 2
      for (int c = t; c < SEQ; c += 256) {
        const bool ok = (mask[c] != 0);
        const float* kr = &kg[((size_t)h * SEQ + c) * HD];
        float a0 = 0.f, a1 = 0.f, a2 = 0.f, a3 = 0.f;
#pragma unroll
        for (int d = 0; d < HD; d += 4) {
          const float4 kv = *(const float4*)&kr[d];
          const float4 qv = *(const float4*)&S.qrow[d];
          a0 = fmaf(qv.x, kv.x, a0);
          a1 = fmaf(qv.y, kv.y, a1);
          a2 = fmaf(qv.z, kv.z, a2);
          a3 = fmaf(qv.w, kv.w, a3);
        }
        const float s = ok ? ((a0 + a1) + (a2 + a3)) : -1e30f;
        lmax = fmaxf(lmax, s);
        S.sc[c] = s;
      }
      const float wm = wave_max(lmax);
      if ((t & 63) == 0) S.red[t >> 6] = wm;
      __syncthreads();
      const float rmax = fmaxf(fmaxf(S.red[0], S.red[1]), fmaxf(S.red[2], S.red[3]));

      float lsum = 0.f;
#pragma unroll 2
      for (int c = t; c < SEQ; c += 256) {
        const float s = S.sc[c];
        const float pp = (s > -1e29f) ? __expf(s - rmax) : 0.0f;
        S.sc[c] = pp;
        lsum += pp;
      }
      const float wsum = wave_sum(lsum);
      __syncthreads();
      if ((t & 63) == 0) S.red[4 + (t >> 6)] = wsum;
      __syncthreads();
      const float rsum = (S.red[4] + S.red[5]) + (S.red[6] + S.red[7]);
      const float inv = 1.0f / rsum;

      const int wv = t >> 6;
      const int d = t & 63;
      float ctx = 0.f;
#pragma unroll 8
      for (int c = wv; c < SEQ; c += 4) {
        ctx = fmaf(S.sc[c], vg[((size_t)h * SEQ + c) * HD + d], ctx);
      }
      S.ctxp[wv][d] = ctx;
      __syncthreads();
      if (t < HD) {
        const float r =
            ((S.ctxp[0][t] + S.ctxp[1][t]) + (S.ctxp[2][t] + S.ctxp[3][t])) * inv;
        out[(size_t)i * DIM + h * HD + t] = r;
      }
    }
  }
}

// ---------------- host ----------------
extern "C" void kernel_launch(void* const* d_in, const int* in_sizes, int n_in,
                              void* d_out, int out_size, void* d_ws, size_t ws_size,
                              hipStream_t stream) {
  const float* hs = (const float*)d_in[0];
  const int* mask = (const int*)d_in[13];

  float* q  = (float*)d_ws;                      // 6 x 4MB fp32 projections
  float* kx = q  + (size_t)SEQ * DIM;
  float* vx = kx + (size_t)SEQ * DIM;            // (vx fp32 unused; slot kept)
  float* qg = vx + (size_t)SEQ * DIM;
  float* kg = qg + (size_t)SEQ * DIM;
  float* vg = kg + (size_t)SEQ * DIM;
  int* gcols = (int*)(vg + (size_t)SEQ * DIM);   // 16KB reserved
  unsigned short* Xcat = (unsigned short*)((char*)gcols + 16384);  // 6MB
  unsigned short* Wcat0 = Xcat + (size_t)SEQ * KCAT;               // 9MB
  unsigned short* qbb = Wcat0 + (size_t)6 * DIM * KCAT;            // 3 x 2MB bf16
  unsigned short* kbb = qbb + (size_t)SEQ * DIM;
  unsigned short* vbb = kbb + (size_t)SEQ * DIM;

  float* out  = (float*)d_out;            // [1,S,DIM]
  float* attn = out + (size_t)SEQ * DIM;  // [1,H,S,S] -- fully kernel-written

  WArgs wa;
  PMArgs pm;
  float* pouts[6] = {q, kx, nullptr, qg, kg, vg};  // vx fp32 dead -> skip
  unsigned short* poutb[6] = {qbb, kbb, vbb, nullptr, nullptr, nullptr};
  for (int p = 0; p < 6; ++p) {
    wa.W[p] = (const float*)d_in[1 + 2 * p];
    wa.Wc[p] = Wcat0 + (size_t)p * DIM * KCAT;
    pm.Wc[p] = wa.Wc[p];
    pm.b[p] = (const float*)d_in[2 + 2 * p];
    pm.out[p] = pouts[p];
    pm.outb[p] = poutb[p];
  }

  hipLaunchKernelGGL(prep_kernel, dim3(2561), dim3(256), 0, stream, hs, Xcat, wa,
                     mask, gcols);

  dim3 g1(SEQ / 128, DIM / 64, 6);
  hipLaunchKernelGGL(proj_mfma_kernel, g1, dim3(256), 0, stream, Xcat, pm);

  hipLaunchKernelGGL(attn_fused_kernel, dim3(1536), dim3(256), 0, stream, qbb, kbb,
                     vbb, q, kx, qg, kg, vg, mask, gcols, out, attn);
}